// Round 17
// baseline (276.577 us; speedup 1.0000x reference)
//
#include <hip/hip_runtime.h>
#include <math.h>

#define TPB 256
static constexpr int N0 = 64;   // nodes per graph
static constexpr int H  = 128;  // hidden
static constexpr int LD = 132;  // stride of the stage-2/3 buffer (bank-skew + 16B aligned)

#define SCHED_FENCE() __builtin_amdgcn_sched_barrier(0)

typedef const __attribute__((address_space(1))) unsigned int glb_u32;
typedef __attribute__((address_space(3))) unsigned int lds_u32;

// 27024 B -> 6 blocks/CU (24 waves; granularity 512 B -> 27136*6 = 162816).
// Misc arrays aliased into dead LDS (lifetimes verified per stage):
//   adjM64  -> B row pads (cols 128..131, 2 ull per row; untouched by data)
//   uu/sv (stage 1)   -> B[0..128) flat   (B dead until x2 recompute)
//   uu/sv (stage 2/3) -> B2[0..128)       (W dbuf dead after its gemm)
//   tv[32] -> B2[2308..2340); sel[32] -> B2[2340..2372); dinv64 -> B2[2372..2436)
// W dbuf (K=128 gemms) -> B2[0..2048)     (z1 dead by then)
struct alignas(16) Shm {
  float B[32 * LD];             // 16896 B
  float B2[2436];               // 9744 B
  float dinvS[32];              // 128 B
  unsigned long long adjS[32];  // 256 B
};

__device__ __forceinline__ unsigned long long& adjPad(float* Bb, int i) {
  return *((unsigned long long*)(Bb + (i >> 1) * LD + 128) + (i & 1));
}

template<int W>
__device__ __forceinline__ float redsum(float v) {
  #pragma unroll
  for (int m = W >> 1; m; m >>= 1) v += __shfl_xor(v, m, 64);
  return v;
}
template<int W>
__device__ __forceinline__ int redsum_i(int v) {
  #pragma unroll
  for (int m = W >> 1; m; m >>= 1) v += __shfl_xor(v, m, 64);
  return v;
}

// In-place normalized aggregation: buf = D^-1/2 (A+I) D^-1/2 buf.
// PADJ: adjacency rows live in B row pads; else flat ull array.
template<int NN, int GROUPS, int CPT, int STRIDE, bool PADJ>
__device__ __forceinline__ void agg_inplace(float* buf, float* adjb,
    const float* dinv, int tid) {
  float acc[CPT];
  const int i = tid & (NN - 1);
  const int g = tid / NN;
  const bool act = (g < GROUPS);
  if (act) {
    unsigned long long m =
        (PADJ ? adjPad(adjb, i) : ((const unsigned long long*)adjb)[i]) | (1ull << i);
    #pragma unroll
    for (int c = 0; c < CPT; ++c) acc[c] = 0.f;
    const float* base = buf + g * CPT;
    #pragma unroll 1
    while (m) {
      int j = __builtin_ctzll(m); m &= m - 1;
      float a = dinv[j];
      const float* xp = base + j * STRIDE;
      #pragma unroll
      for (int c = 0; c < CPT; c += 4) {
        float4 xv = *(const float4*)(xp + c);
        acc[c]     += a * xv.x; acc[c + 1] += a * xv.y;
        acc[c + 2] += a * xv.z; acc[c + 3] += a * xv.w;
      }
    }
    float di = dinv[i];
    #pragma unroll
    for (int c = 0; c < CPT; ++c) acc[c] *= di;
  }
  __syncthreads();
  if (act) {
    float* op = buf + i * STRIDE + g * CPT;
    #pragma unroll
    for (int c = 0; c < CPT; c += 4)
      *(float4*)(op + c) = make_float4(acc[c], acc[c + 1], acc[c + 2], acc[c + 3]);
  }
  __syncthreads();
  SCHED_FENCE();
}

// Stage-1 GEMM (K=36), W streamed from global in float4 (4 cols/thread), depth-1.
// MODE 1: y in regs; u=y.wl, v=y.wr via redsum<32> -> uuP, svP.
// MODE 2: rows gathered via selP; out[r][fc..] = relu(acc+b) * tvP[r].
template<int R, int K, int KREAL, int MODE>
__device__ __forceinline__ void gemm_gw(const float* z, int zld,
    const float* __restrict__ Wg, const float* __restrict__ bg,
    float* out, int old_,
    const float* __restrict__ wl, const float* __restrict__ wr,
    float* uuP, float* svP, const float* tvP, const int* selP, int tid) {
  constexpr int NR = R / 8;
  constexpr int KC = 4;
  const int fc = (tid & 31) * 4;
  const int r0 = (tid >> 5) * NR;
  float4 acc[NR];
  int zoff[NR];
  #pragma unroll
  for (int r = 0; r < NR; ++r) {
    acc[r] = make_float4(0.f, 0.f, 0.f, 0.f);
    int row = (MODE == 2) ? selP[r0 + r] : (r0 + r);
    zoff[r] = row * zld;
  }
  float4 w[KC], nw[KC];
  #pragma unroll
  for (int k = 0; k < KC; ++k)
    w[k] = (k < KREAL) ? *(const float4*)(Wg + k * H + fc)
                       : make_float4(0.f, 0.f, 0.f, 0.f);
  #pragma unroll 1
  for (int kt = 0; kt < K; kt += KC) {
    if (kt + KC < K) {
      #pragma unroll
      for (int k = 0; k < KC; ++k) {
        int gr = kt + KC + k;
        nw[k] = (gr < KREAL) ? *(const float4*)(Wg + gr * H + fc)
                             : make_float4(0.f, 0.f, 0.f, 0.f);
      }
    }
    #pragma unroll
    for (int r = 0; r < NR; ++r) {
      float4 zv = *(const float4*)(z + zoff[r] + kt);
      acc[r].x += zv.x * w[0].x + zv.y * w[1].x + zv.z * w[2].x + zv.w * w[3].x;
      acc[r].y += zv.x * w[0].y + zv.y * w[1].y + zv.z * w[2].y + zv.w * w[3].y;
      acc[r].z += zv.x * w[0].z + zv.y * w[1].z + zv.z * w[2].z + zv.w * w[3].z;
      acc[r].w += zv.x * w[0].w + zv.y * w[1].w + zv.z * w[2].w + zv.w * w[3].w;
    }
    #pragma unroll
    for (int k = 0; k < KC; ++k) w[k] = nw[k];
  }
  const float4 b4 = *(const float4*)(bg + fc);
  if constexpr (MODE == 1) {
    const float4 wl4 = *(const float4*)(wl + fc);
    const float4 wr4 = *(const float4*)(wr + fc);
    #pragma unroll
    for (int r = 0; r < NR; ++r) {
      float y0 = fmaxf(acc[r].x + b4.x, 0.f);
      float y1 = fmaxf(acc[r].y + b4.y, 0.f);
      float y2 = fmaxf(acc[r].z + b4.z, 0.f);
      float y3 = fmaxf(acc[r].w + b4.w, 0.f);
      float up = y0 * wl4.x + y1 * wl4.y + y2 * wl4.z + y3 * wl4.w;
      float vp = y0 * wr4.x + y1 * wr4.y + y2 * wr4.z + y3 * wr4.w;
      up = redsum<32>(up);
      vp = redsum<32>(vp);
      if ((tid & 31) == 0) { uuP[r0 + r] = up; svP[r0 + r] = vp; }
    }
  } else {
    #pragma unroll
    for (int r = 0; r < NR; ++r) {
      float t = (MODE == 2) ? tvP[r0 + r] : 1.f;
      float4 o;
      o.x = fmaxf(acc[r].x + b4.x, 0.f) * t;
      o.y = fmaxf(acc[r].y + b4.y, 0.f) * t;
      o.z = fmaxf(acc[r].z + b4.z, 0.f) * t;
      o.w = fmaxf(acc[r].w + b4.w, 0.f) * t;
      *(float4*)(out + (r0 + r) * old_ + fc) = o;
    }
  }
}

// Async-DMA one 8-row W tile (8x128 floats = 4096 B, contiguous in global)
// into LDS: 4 waves x 1024 B each. LDS dest wave-uniform; global src per-lane.
__device__ __forceinline__ void stage_w8(const float* gsrc, float* ldst,
                                         int wv, int ln) {
  __builtin_amdgcn_global_load_lds(
      (glb_u32*)(gsrc + wv * 256 + ln * 4),
      (lds_u32*)(ldst + wv * 256),
      16, 0, 0);
}

// K=KREAL=128 GEMM, in-place (out aliases z), W tiles double-buffered in LDS
// (wt0/wt1, 1024 floats each) via async global_load_lds. Ascending-k order.
// R15 lesson: never register-double-buffer W (allocator spills to scratch).
template<int R>
__device__ __forceinline__ void gemm128_lds(float* zb,
    float* wt0, float* wt1,
    const float* __restrict__ Wg, const float* __restrict__ bg, int tid) {
  constexpr int NR = R / 8;
  const int fc = (tid & 31) * 4;
  const int r0 = (tid >> 5) * NR;
  const int wv = tid >> 6;
  const int ln = tid & 63;
  float4 acc[NR];
  int zoff[NR];
  #pragma unroll
  for (int r = 0; r < NR; ++r) {
    acc[r] = make_float4(0.f, 0.f, 0.f, 0.f);
    zoff[r] = (r0 + r) * LD;
  }
  stage_w8(Wg, wt0, wv, ln);
  asm volatile("s_waitcnt vmcnt(0)" ::: "memory");
  __syncthreads();
  #pragma unroll 1
  for (int kt = 0; kt < 128; kt += 8) {
    const int t = kt >> 3;
    const float* cur = (t & 1) ? wt1 : wt0;
    float* nxt = (t & 1) ? wt0 : wt1;
    if (kt + 8 < 128) stage_w8(Wg + (kt + 8) * H, nxt, wv, ln);
    #pragma unroll
    for (int kc = 0; kc < 8; kc += 4) {
      float4 w0 = *(const float4*)(cur + (kc + 0) * H + fc);
      float4 w1 = *(const float4*)(cur + (kc + 1) * H + fc);
      float4 w2 = *(const float4*)(cur + (kc + 2) * H + fc);
      float4 w3 = *(const float4*)(cur + (kc + 3) * H + fc);
      #pragma unroll
      for (int r = 0; r < NR; ++r) {
        float4 zv = *(const float4*)(zb + zoff[r] + kt + kc);
        acc[r].x += zv.x * w0.x + zv.y * w1.x + zv.z * w2.x + zv.w * w3.x;
        acc[r].y += zv.x * w0.y + zv.y * w1.y + zv.z * w2.y + zv.w * w3.y;
        acc[r].z += zv.x * w0.z + zv.y * w1.z + zv.z * w2.z + zv.w * w3.z;
        acc[r].w += zv.x * w0.w + zv.y * w1.w + zv.z * w2.w + zv.w * w3.w;
      }
    }
    asm volatile("s_waitcnt vmcnt(0)" ::: "memory");
    __syncthreads();   // next tile ready; final iter: all z reads complete
  }
  const float4 b4 = *(const float4*)(bg + fc);
  #pragma unroll
  for (int r = 0; r < NR; ++r) {
    float4 o;
    o.x = fmaxf(acc[r].x + b4.x, 0.f);
    o.y = fmaxf(acc[r].y + b4.y, 0.f);
    o.z = fmaxf(acc[r].z + b4.z, 0.f);
    o.w = fmaxf(acc[r].w + b4.w, 0.f);
    *(float4*)(zb + zoff[r] + fc) = o;
  }
}

// s[i] = sum_{j in nbr(i)} u[j] + bl + v[i]   (v already in sv[i])
template<int NN, bool PADJ>
__device__ __forceinline__ void score(float* adjb, const float* uu, float* sv,
                                      float bl, int tid) {
  if (tid < NN) {
    unsigned long long m =
        PADJ ? adjPad(adjb, tid) : ((const unsigned long long*)adjb)[tid];
    float a = bl + sv[tid];
    #pragma unroll 1
    while (m) { int j = __builtin_ctzll(m); m &= m - 1; a += uu[j]; }
    sv[tid] = a;
  }
}

// exact stable top-k via parallel rank counting (NN*RKP == TPB)
template<int NN, int KK, int RKP>
__device__ __forceinline__ void rank_topk(const float* sv, float* tv, int* sel,
                                          int tid) {
  int i = tid / RKP, p = tid % RKP;
  constexpr int CHr = NN / RKP;
  float si = sv[i];
  int cnt = 0;
  #pragma unroll
  for (int c = 0; c < CHr; ++c) {
    int j = p * CHr + c;
    float sj = sv[j];
    cnt += (sj > si || (sj == si && j < i)) ? 1 : 0;
  }
  cnt = redsum_i<RKP>(cnt);
  if (p == 0 && cnt < KK) { sel[cnt] = i; tv[cnt] = tanhf(si); }
}

// readout accumulate over KK rows of xn (stride ld)
template<int KK>
__device__ __forceinline__ void readout(const float* xn, int ld, int tid,
                                        float& rm, float& rs) {
  if (tid < H) {
    float m = -INFINITY, s = 0.f;
    #pragma unroll
    for (int r = 0; r < KK; ++r) {
      float v = xn[r * ld + tid];
      m = fmaxf(m, v); s += v;
    }
    rm += m;
    rs += s * (1.f / KK);
  }
}

// SAGPool for stages 2/3, fully IN PLACE on x (= y, stride LD).
template<int NN, int KK, int UVP, int RKP, bool DOFILT>
__device__ __forceinline__ void sag_pool_inplace(Shm& sh, float* x,
    const float* __restrict__ wl, const float* __restrict__ blp,
    const float* __restrict__ wr,
    float* uu, float* sv, float* tv, int* sel, int tid, float& rm, float& rs) {
  { // u[j]=y[j].wl -> uu, v[j]=y[j].wr -> sv  (2*NN*UVP == TPB)
    int dot = tid / UVP, p = tid % UVP;
    int j = dot >> 1;
    const float* wp = (dot & 1) ? wr : wl;
    constexpr int CH = H / UVP;
    const float* xr = x + j * LD + p * CH;
    const float* wq = wp + p * CH;
    float a = 0.f;
    #pragma unroll
    for (int k = 0; k < CH; k += 4) {
      float4 xv = *(const float4*)(xr + k);
      float4 wv = *(const float4*)(wq + k);
      a += xv.x * wv.x + xv.y * wv.y + xv.z * wv.z + xv.w * wv.w;
    }
    a = redsum<UVP>(a);
    if (p == 0) { if (dot & 1) sv[j] = a; else uu[j] = a; }
  }
  __syncthreads();
  SCHED_FENCE();
  score<NN, false>((float*)sh.adjS, uu, sv, blp[0], tid);
  __syncthreads();
  rank_topk<NN, KK, RKP>(sv, tv, sel, tid);
  __syncthreads();
  SCHED_FENCE();
  // snapshot old rows; reg-staged in-place gather x[r] = y[sel[r]] * tv[r]
  unsigned long long oldrow = 0ull;
  if (tid < KK) oldrow = sh.adjS[sel[tid]];
  constexpr int NV  = KK * (H / 4);
  constexpr int PER = (NV + TPB - 1) / TPB;
  float4 stg[PER]; int dst[PER];
  #pragma unroll
  for (int q = 0; q < PER; ++q) {
    int e = tid + q * TPB;
    if (e < NV) {
      int r = e / (H / 4), c = (e % (H / 4)) * 4;
      float4 v = *(const float4*)(x + sel[r] * LD + c);
      float t = tv[r];
      stg[q] = make_float4(v.x * t, v.y * t, v.z * t, v.w * t);
      dst[q] = r * LD + c;
    }
  }
  __syncthreads();
  #pragma unroll
  for (int q = 0; q < PER; ++q) {
    int e = tid + q * TPB;
    if (e < NV) *(float4*)(x + dst[q]) = stg[q];
  }
  __syncthreads();
  SCHED_FENCE();
  if (DOFILT && tid < KK) {
    unsigned long long nm = 0ull;
    #pragma unroll 1
    for (int c = 0; c < KK; ++c)
      nm |= ((oldrow >> sel[c]) & 1ull) << c;
    sh.adjS[tid] = nm;
    sh.dinvS[tid] = rsqrtf(1.f + (float)__popcll(nm));
  }
  readout<KK>(x, LD, tid, rm, rs);
  __syncthreads();
  SCHED_FENCE();
}

__global__ __launch_bounds__(TPB, 6) void sagpool_fused(
    const int* __restrict__ aa, const float* __restrict__ pos,
    const float* __restrict__ cdr, const float* __restrict__ adjG,
    const float* __restrict__ emb,
    const float* __restrict__ W1, const float* __restrict__ b1,
    const float* __restrict__ p1wl, const float* __restrict__ p1bl, const float* __restrict__ p1wr,
    const float* __restrict__ W2, const float* __restrict__ b2,
    const float* __restrict__ p2wl, const float* __restrict__ p2bl, const float* __restrict__ p2wr,
    const float* __restrict__ W3, const float* __restrict__ b3,
    const float* __restrict__ p3wl, const float* __restrict__ p3bl, const float* __restrict__ p3wr,
    const float* __restrict__ mW1, const float* __restrict__ mb1,
    const float* __restrict__ mW2, const float* __restrict__ mb2,
    const float* __restrict__ mW3, const float* __restrict__ mb3,
    float* __restrict__ out)
{
  __shared__ Shm sh;
  const int b   = blockIdx.x;
  const int tid = threadIdx.x;

  float* dinv64 = sh.B2 + 2372;            // [2372..2436)
  float* tvP    = sh.B2 + 2308;            // [2308..2340)
  int*   selP   = (int*)(sh.B2 + 2340);    // [2340..2372)
  float* uu1 = sh.B;        float* sv1 = sh.B + 64;    // stage-1 (B dead)
  float* uu23 = sh.B2;      float* sv23 = sh.B2 + 64;  // stages 2/3 (dbuf dead)

  float rm = 0.f, rs = 0.f;   // readout accumulators (feature = tid, tid < 128)

  // adjacency [64][64] -> 64-bit row masks (B row pads) + fused degree/dinv
  {
    const float* rp = adjG + (size_t)b * (N0 * N0) + (tid >> 2) * N0 + (tid & 3) * 16;
    unsigned long long mpart = 0ull;
    #pragma unroll
    for (int q = 0; q < 16; q += 4) {
      float4 v = *(const float4*)(rp + q);
      unsigned int bits = (v.x != 0.f ? 1u : 0u) | (v.y != 0.f ? 2u : 0u)
                        | (v.z != 0.f ? 4u : 0u) | (v.w != 0.f ? 8u : 0u);
      mpart |= (unsigned long long)bits << q;
    }
    mpart <<= ((tid & 3) * 16);
    mpart |= __shfl_xor(mpart, 1, 64);
    mpart |= __shfl_xor(mpart, 2, 64);
    if ((tid & 3) == 0) {
      int r = tid >> 2;
      adjPad(sh.B, r) = mpart;
      dinv64[r] = rsqrtf(1.f + (float)__popcll(mpart));
    }
  }
  SCHED_FENCE();
  // build xin = [emb[aa] | pos | is_cdr3 | 0 0] -> B2 [64][36]
  #pragma unroll 1
  for (int e = tid; e < N0 * 36; e += TPB) {
    int j = e / 36, k = e - j * 36;
    int node = b * N0 + j;
    float v;
    if (k < 32)       v = emb[aa[node] * 32 + k];
    else if (k == 32) v = pos[node];
    else if (k == 33) v = cdr[node];
    else              v = 0.f;
    sh.B2[e] = v;
  }
  __syncthreads();
  SCHED_FENCE();

  // ---- stage 1: GCN(34->128) on 64 nodes, pool 64->32 (y1 never stored) ----
  agg_inplace<64, 3, 12, 36, true>(sh.B2, sh.B, dinv64, tid);  // xin -> z1 in place
  gemm_gw<64, 36, 34, 1>(sh.B2, 36, W1, b1, nullptr, 0, p1wl, p1wr,
                         uu1, sv1, nullptr, nullptr, tid);
  __syncthreads();
  SCHED_FENCE();
  score<64, true>(sh.B, uu1, sv1, p1bl[0], tid);
  __syncthreads();
  rank_topk<64, 32, 4>(sv1, tvP, selP, tid);
  __syncthreads();
  SCHED_FENCE();
  gemm_gw<32, 36, 34, 2>(sh.B2, 36, W1, b1, sh.B, LD, nullptr, nullptr,
                         nullptr, nullptr, tvP, selP, tid);    // x2 -> B rows 0..31
  __syncthreads();
  SCHED_FENCE();
  if (tid < 32) {   // adjPad rows still valid (cols 128+ untouched by x2)
    unsigned long long oldrow = adjPad(sh.B, selP[tid]);
    unsigned long long nm = 0ull;
    #pragma unroll 1
    for (int c = 0; c < 32; ++c)
      nm |= ((oldrow >> selP[c]) & 1ull) << c;
    sh.adjS[tid] = nm;
    sh.dinvS[tid] = rsqrtf(1.f + (float)__popcll(nm));
  }
  readout<32>(sh.B, LD, tid, rm, rs);
  __syncthreads();
  SCHED_FENCE();

  // ---- stage 2: GCN(128->128) on 32 nodes, pool 32->16 ----
  agg_inplace<32, 8, 16, LD, false>(sh.B, (float*)sh.adjS, sh.dinvS, tid);
  gemm128_lds<32>(sh.B, sh.B2, sh.B2 + 1024, W2, b2, tid);     // y2 in place
  __syncthreads();
  SCHED_FENCE();
  sag_pool_inplace<32, 16, 4, 8, true>(sh, sh.B, p2wl, p2bl, p2wr,
                                       uu23, sv23, tvP, selP, tid, rm, rs);

  // ---- stage 3: GCN(128->128) on 16 nodes, pool 16->8 ----
  agg_inplace<16, 16, 8, LD, false>(sh.B, (float*)sh.adjS, sh.dinvS, tid);
  gemm128_lds<16>(sh.B, sh.B2, sh.B2 + 1024, W3, b3, tid);     // y3 in place
  __syncthreads();
  SCHED_FENCE();
  sag_pool_inplace<16, 8, 8, 16, false>(sh, sh.B, p3wl, p3bl, p3wr,
                                        uu23, sv23, tvP, selP, tid, rm, rs);

  // ---- MLP head (B2[0..896) dead: rbuf[0..256) | h1[256..384) | h1p[384..640) | h2p[640..896)) ----
  if (tid < H) { sh.B2[tid] = rm; sh.B2[H + tid] = rs; }
  __syncthreads();
  SCHED_FENCE();
  { // h1 partials: 128 f x 2 k-halves
    int f = tid & (H - 1), p = tid >> 7;
    const int base = p * 128;
    float a = 0.f;
    #pragma unroll 4
    for (int k = 0; k < 128; ++k) a += sh.B2[base + k] * mW1[(base + k) * H + f];
    sh.B2[384 + p * H + f] = a;
  }
  __syncthreads();
  SCHED_FENCE();
  if (tid < H) {
    float a = mb1[tid] + sh.B2[384 + tid] + sh.B2[384 + H + tid];
    sh.B2[256 + tid] = fmaxf(a, 0.f);
  }
  __syncthreads();
  SCHED_FENCE();
  { // h2 partials: 64 o x 4 k-parts
    int o = tid & 63, p = tid >> 6;
    const int base = p * 32;
    float a = 0.f;
    #pragma unroll 4
    for (int k = 0; k < 32; ++k) a += sh.B2[256 + base + k] * mW2[(base + k) * 64 + o];
    sh.B2[640 + p * 64 + o] = a;
  }
  __syncthreads();
  SCHED_FENCE();
  if (tid < 64) {
    float a = sh.B2[640 + tid] + sh.B2[704 + tid] + sh.B2[768 + tid] + sh.B2[832 + tid];
    a = fmaxf(a + mb2[tid], 0.f);
    float v = a * mW3[tid];
    v = redsum<64>(v);
    if (tid == 0) out[b] = v + mb3[0];
  }
}

extern "C" void kernel_launch(void* const* d_in, const int* in_sizes, int n_in,
                              void* d_out, int out_size, void* d_ws, size_t ws_size,
                              hipStream_t stream) {
  (void)n_in; (void)d_ws; (void)ws_size; (void)out_size;
  const int*   aa   = (const int*)  d_in[0];
  const float* pos  = (const float*)d_in[1];
  const float* cdr  = (const float*)d_in[2];
  const float* adj  = (const float*)d_in[3];
  const float* emb  = (const float*)d_in[4];
  const float* W1   = (const float*)d_in[5];
  const float* b1   = (const float*)d_in[6];
  const float* p1wl = (const float*)d_in[7];
  const float* p1bl = (const float*)d_in[8];
  const float* p1wr = (const float*)d_in[9];
  const float* W2   = (const float*)d_in[10];
  const float* b2   = (const float*)d_in[11];
  const float* p2wl = (const float*)d_in[12];
  const float* p2bl = (const float*)d_in[13];
  const float* p2wr = (const float*)d_in[14];
  const float* W3   = (const float*)d_in[15];
  const float* b3   = (const float*)d_in[16];
  const float* p3wl = (const float*)d_in[17];
  const float* p3bl = (const float*)d_in[18];
  const float* p3wr = (const float*)d_in[19];
  const float* mW1  = (const float*)d_in[20];
  const float* mb1  = (const float*)d_in[21];
  const float* mW2  = (const float*)d_in[22];
  const float* mb2  = (const float*)d_in[23];
  const float* mW3  = (const float*)d_in[24];
  const float* mb3  = (const float*)d_in[25];
  float* out = (float*)d_out;

  const int B = in_sizes[0] / N0;  // 4096
  hipLaunchKernelGGL(sagpool_fused, dim3(B), dim3(TPB), 0, stream,
                     aa, pos, cdr, adj, emb,
                     W1, b1, p1wl, p1bl, p1wr,
                     W2, b2, p2wl, p2bl, p2wr,
                     W3, b3, p3wl, p3bl, p3wr,
                     mW1, mb1, mW2, mb2, mW3, mb3, out);
}

// Round 18
// 245.658 us; speedup vs baseline: 1.1259x; 1.1259x over previous
//
#include <hip/hip_runtime.h>
#include <math.h>

#define TPB 256
static constexpr int N0 = 64;   // nodes per graph
static constexpr int H  = 128;  // hidden
static constexpr int LD = 132;  // stride of the stage-2/3 buffer (bank-skew + 16B aligned)

#define SCHED_FENCE() __builtin_amdgcn_sched_barrier(0)

typedef const __attribute__((address_space(1))) unsigned int glb_u32;
typedef __attribute__((address_space(3))) unsigned int lds_u32;

// 27024 B -> 6 blocks/CU by LDS (27136*6 = 162816 <= 163840).
// R17 lesson: do NOT declare launch_bounds(.,6) — the 6-wave guarantee forces
// the allocator to 40 VGPR + scratch spills (WRITE 120 MB). Declare 5 (the
// no-spill budget, VGPR~48); HW still co-resides 6 blocks since actual
// VGPR (48 -> 10 waves/SIMD) and LDS permit it.
// Misc arrays aliased into dead LDS (lifetimes verified per stage):
//   adjM64  -> B row pads (cols 128..131, 2 ull per row; untouched by data)
//   uu/sv (stage 1)   -> B[0..128) flat   (B dead until x2 recompute)
//   uu/sv (stage 2/3) -> B2[0..128)       (W dbuf dead after its gemm)
//   tv[32] -> B2[2308..2340); sel[32] -> B2[2340..2372); dinv64 -> B2[2372..2436)
// W dbuf (K=128 gemms) -> B2[0..2048)     (z1 dead by then)
struct alignas(16) Shm {
  float B[32 * LD];             // 16896 B
  float B2[2436];               // 9744 B
  float dinvS[32];              // 128 B
  unsigned long long adjS[32];  // 256 B
};

__device__ __forceinline__ unsigned long long& adjPad(float* Bb, int i) {
  return *((unsigned long long*)(Bb + (i >> 1) * LD + 128) + (i & 1));
}

template<int W>
__device__ __forceinline__ float redsum(float v) {
  #pragma unroll
  for (int m = W >> 1; m; m >>= 1) v += __shfl_xor(v, m, 64);
  return v;
}
template<int W>
__device__ __forceinline__ int redsum_i(int v) {
  #pragma unroll
  for (int m = W >> 1; m; m >>= 1) v += __shfl_xor(v, m, 64);
  return v;
}

// In-place normalized aggregation: buf = D^-1/2 (A+I) D^-1/2 buf.
// PADJ: adjacency rows live in B row pads; else flat ull array.
template<int NN, int GROUPS, int CPT, int STRIDE, bool PADJ>
__device__ __forceinline__ void agg_inplace(float* buf, float* adjb,
    const float* dinv, int tid) {
  float acc[CPT];
  const int i = tid & (NN - 1);
  const int g = tid / NN;
  const bool act = (g < GROUPS);
  if (act) {
    unsigned long long m =
        (PADJ ? adjPad(adjb, i) : ((const unsigned long long*)adjb)[i]) | (1ull << i);
    #pragma unroll
    for (int c = 0; c < CPT; ++c) acc[c] = 0.f;
    const float* base = buf + g * CPT;
    #pragma unroll 1
    while (m) {
      int j = __builtin_ctzll(m); m &= m - 1;
      float a = dinv[j];
      const float* xp = base + j * STRIDE;
      #pragma unroll
      for (int c = 0; c < CPT; c += 4) {
        float4 xv = *(const float4*)(xp + c);
        acc[c]     += a * xv.x; acc[c + 1] += a * xv.y;
        acc[c + 2] += a * xv.z; acc[c + 3] += a * xv.w;
      }
    }
    float di = dinv[i];
    #pragma unroll
    for (int c = 0; c < CPT; ++c) acc[c] *= di;
  }
  __syncthreads();
  if (act) {
    float* op = buf + i * STRIDE + g * CPT;
    #pragma unroll
    for (int c = 0; c < CPT; c += 4)
      *(float4*)(op + c) = make_float4(acc[c], acc[c + 1], acc[c + 2], acc[c + 3]);
  }
  __syncthreads();
  SCHED_FENCE();
}

// Stage-1 GEMM (K=36), W streamed from global in float4 (4 cols/thread), depth-1.
// MODE 1: y in regs; u=y.wl, v=y.wr via redsum<32> -> uuP, svP.
// MODE 2: rows gathered via selP; out[r][fc..] = relu(acc+b) * tvP[r].
template<int R, int K, int KREAL, int MODE>
__device__ __forceinline__ void gemm_gw(const float* z, int zld,
    const float* __restrict__ Wg, const float* __restrict__ bg,
    float* out, int old_,
    const float* __restrict__ wl, const float* __restrict__ wr,
    float* uuP, float* svP, const float* tvP, const int* selP, int tid) {
  constexpr int NR = R / 8;
  constexpr int KC = 4;
  const int fc = (tid & 31) * 4;
  const int r0 = (tid >> 5) * NR;
  float4 acc[NR];
  int zoff[NR];
  #pragma unroll
  for (int r = 0; r < NR; ++r) {
    acc[r] = make_float4(0.f, 0.f, 0.f, 0.f);
    int row = (MODE == 2) ? selP[r0 + r] : (r0 + r);
    zoff[r] = row * zld;
  }
  float4 w[KC], nw[KC];
  #pragma unroll
  for (int k = 0; k < KC; ++k)
    w[k] = (k < KREAL) ? *(const float4*)(Wg + k * H + fc)
                       : make_float4(0.f, 0.f, 0.f, 0.f);
  #pragma unroll 1
  for (int kt = 0; kt < K; kt += KC) {
    if (kt + KC < K) {
      #pragma unroll
      for (int k = 0; k < KC; ++k) {
        int gr = kt + KC + k;
        nw[k] = (gr < KREAL) ? *(const float4*)(Wg + gr * H + fc)
                             : make_float4(0.f, 0.f, 0.f, 0.f);
      }
    }
    #pragma unroll
    for (int r = 0; r < NR; ++r) {
      float4 zv = *(const float4*)(z + zoff[r] + kt);
      acc[r].x += zv.x * w[0].x + zv.y * w[1].x + zv.z * w[2].x + zv.w * w[3].x;
      acc[r].y += zv.x * w[0].y + zv.y * w[1].y + zv.z * w[2].y + zv.w * w[3].y;
      acc[r].z += zv.x * w[0].z + zv.y * w[1].z + zv.z * w[2].z + zv.w * w[3].z;
      acc[r].w += zv.x * w[0].w + zv.y * w[1].w + zv.z * w[2].w + zv.w * w[3].w;
    }
    #pragma unroll
    for (int k = 0; k < KC; ++k) w[k] = nw[k];
  }
  const float4 b4 = *(const float4*)(bg + fc);
  if constexpr (MODE == 1) {
    const float4 wl4 = *(const float4*)(wl + fc);
    const float4 wr4 = *(const float4*)(wr + fc);
    #pragma unroll
    for (int r = 0; r < NR; ++r) {
      float y0 = fmaxf(acc[r].x + b4.x, 0.f);
      float y1 = fmaxf(acc[r].y + b4.y, 0.f);
      float y2 = fmaxf(acc[r].z + b4.z, 0.f);
      float y3 = fmaxf(acc[r].w + b4.w, 0.f);
      float up = y0 * wl4.x + y1 * wl4.y + y2 * wl4.z + y3 * wl4.w;
      float vp = y0 * wr4.x + y1 * wr4.y + y2 * wr4.z + y3 * wr4.w;
      up = redsum<32>(up);
      vp = redsum<32>(vp);
      if ((tid & 31) == 0) { uuP[r0 + r] = up; svP[r0 + r] = vp; }
    }
  } else {
    #pragma unroll
    for (int r = 0; r < NR; ++r) {
      float t = (MODE == 2) ? tvP[r0 + r] : 1.f;
      float4 o;
      o.x = fmaxf(acc[r].x + b4.x, 0.f) * t;
      o.y = fmaxf(acc[r].y + b4.y, 0.f) * t;
      o.z = fmaxf(acc[r].z + b4.z, 0.f) * t;
      o.w = fmaxf(acc[r].w + b4.w, 0.f) * t;
      *(float4*)(out + (r0 + r) * old_ + fc) = o;
    }
  }
}

// Async-DMA one 8-row W tile (8x128 floats = 4096 B, contiguous in global)
// into LDS: 4 waves x 1024 B each. LDS dest wave-uniform; global src per-lane.
__device__ __forceinline__ void stage_w8(const float* gsrc, float* ldst,
                                         int wv, int ln) {
  __builtin_amdgcn_global_load_lds(
      (glb_u32*)(gsrc + wv * 256 + ln * 4),
      (lds_u32*)(ldst + wv * 256),
      16, 0, 0);
}

// K=KREAL=128 GEMM, in-place (out aliases z), W tiles double-buffered in LDS
// (wt0/wt1, 1024 floats each) via async global_load_lds. Ascending-k order.
// R15 lesson: never register-double-buffer W (allocator spills to scratch).
template<int R>
__device__ __forceinline__ void gemm128_lds(float* zb,
    float* wt0, float* wt1,
    const float* __restrict__ Wg, const float* __restrict__ bg, int tid) {
  constexpr int NR = R / 8;
  const int fc = (tid & 31) * 4;
  const int r0 = (tid >> 5) * NR;
  const int wv = tid >> 6;
  const int ln = tid & 63;
  float4 acc[NR];
  int zoff[NR];
  #pragma unroll
  for (int r = 0; r < NR; ++r) {
    acc[r] = make_float4(0.f, 0.f, 0.f, 0.f);
    zoff[r] = (r0 + r) * LD;
  }
  stage_w8(Wg, wt0, wv, ln);
  asm volatile("s_waitcnt vmcnt(0)" ::: "memory");
  __syncthreads();
  #pragma unroll 1
  for (int kt = 0; kt < 128; kt += 8) {
    const int t = kt >> 3;
    const float* cur = (t & 1) ? wt1 : wt0;
    float* nxt = (t & 1) ? wt0 : wt1;
    if (kt + 8 < 128) stage_w8(Wg + (kt + 8) * H, nxt, wv, ln);
    #pragma unroll
    for (int kc = 0; kc < 8; kc += 4) {
      float4 w0 = *(const float4*)(cur + (kc + 0) * H + fc);
      float4 w1 = *(const float4*)(cur + (kc + 1) * H + fc);
      float4 w2 = *(const float4*)(cur + (kc + 2) * H + fc);
      float4 w3 = *(const float4*)(cur + (kc + 3) * H + fc);
      #pragma unroll
      for (int r = 0; r < NR; ++r) {
        float4 zv = *(const float4*)(zb + zoff[r] + kt + kc);
        acc[r].x += zv.x * w0.x + zv.y * w1.x + zv.z * w2.x + zv.w * w3.x;
        acc[r].y += zv.x * w0.y + zv.y * w1.y + zv.z * w2.y + zv.w * w3.y;
        acc[r].z += zv.x * w0.z + zv.y * w1.z + zv.z * w2.z + zv.w * w3.z;
        acc[r].w += zv.x * w0.w + zv.y * w1.w + zv.z * w2.w + zv.w * w3.w;
      }
    }
    asm volatile("s_waitcnt vmcnt(0)" ::: "memory");
    __syncthreads();   // next tile ready; final iter: all z reads complete
  }
  const float4 b4 = *(const float4*)(bg + fc);
  #pragma unroll
  for (int r = 0; r < NR; ++r) {
    float4 o;
    o.x = fmaxf(acc[r].x + b4.x, 0.f);
    o.y = fmaxf(acc[r].y + b4.y, 0.f);
    o.z = fmaxf(acc[r].z + b4.z, 0.f);
    o.w = fmaxf(acc[r].w + b4.w, 0.f);
    *(float4*)(zb + zoff[r] + fc) = o;
  }
}

// s[i] = sum_{j in nbr(i)} u[j] + bl + v[i]   (v already in sv[i])
template<int NN, bool PADJ>
__device__ __forceinline__ void score(float* adjb, const float* uu, float* sv,
                                      float bl, int tid) {
  if (tid < NN) {
    unsigned long long m =
        PADJ ? adjPad(adjb, tid) : ((const unsigned long long*)adjb)[tid];
    float a = bl + sv[tid];
    #pragma unroll 1
    while (m) { int j = __builtin_ctzll(m); m &= m - 1; a += uu[j]; }
    sv[tid] = a;
  }
}

// exact stable top-k via parallel rank counting (NN*RKP == TPB)
template<int NN, int KK, int RKP>
__device__ __forceinline__ void rank_topk(const float* sv, float* tv, int* sel,
                                          int tid) {
  int i = tid / RKP, p = tid % RKP;
  constexpr int CHr = NN / RKP;
  float si = sv[i];
  int cnt = 0;
  #pragma unroll
  for (int c = 0; c < CHr; ++c) {
    int j = p * CHr + c;
    float sj = sv[j];
    cnt += (sj > si || (sj == si && j < i)) ? 1 : 0;
  }
  cnt = redsum_i<RKP>(cnt);
  if (p == 0 && cnt < KK) { sel[cnt] = i; tv[cnt] = tanhf(si); }
}

// readout accumulate over KK rows of xn (stride ld)
template<int KK>
__device__ __forceinline__ void readout(const float* xn, int ld, int tid,
                                        float& rm, float& rs) {
  if (tid < H) {
    float m = -INFINITY, s = 0.f;
    #pragma unroll
    for (int r = 0; r < KK; ++r) {
      float v = xn[r * ld + tid];
      m = fmaxf(m, v); s += v;
    }
    rm += m;
    rs += s * (1.f / KK);
  }
}

// SAGPool for stages 2/3, fully IN PLACE on x (= y, stride LD).
template<int NN, int KK, int UVP, int RKP, bool DOFILT>
__device__ __forceinline__ void sag_pool_inplace(Shm& sh, float* x,
    const float* __restrict__ wl, const float* __restrict__ blp,
    const float* __restrict__ wr,
    float* uu, float* sv, float* tv, int* sel, int tid, float& rm, float& rs) {
  { // u[j]=y[j].wl -> uu, v[j]=y[j].wr -> sv  (2*NN*UVP == TPB)
    int dot = tid / UVP, p = tid % UVP;
    int j = dot >> 1;
    const float* wp = (dot & 1) ? wr : wl;
    constexpr int CH = H / UVP;
    const float* xr = x + j * LD + p * CH;
    const float* wq = wp + p * CH;
    float a = 0.f;
    #pragma unroll
    for (int k = 0; k < CH; k += 4) {
      float4 xv = *(const float4*)(xr + k);
      float4 wv = *(const float4*)(wq + k);
      a += xv.x * wv.x + xv.y * wv.y + xv.z * wv.z + xv.w * wv.w;
    }
    a = redsum<UVP>(a);
    if (p == 0) { if (dot & 1) sv[j] = a; else uu[j] = a; }
  }
  __syncthreads();
  SCHED_FENCE();
  score<NN, false>((float*)sh.adjS, uu, sv, blp[0], tid);
  __syncthreads();
  rank_topk<NN, KK, RKP>(sv, tv, sel, tid);
  __syncthreads();
  SCHED_FENCE();
  // snapshot old rows; reg-staged in-place gather x[r] = y[sel[r]] * tv[r]
  unsigned long long oldrow = 0ull;
  if (tid < KK) oldrow = sh.adjS[sel[tid]];
  constexpr int NV  = KK * (H / 4);
  constexpr int PER = (NV + TPB - 1) / TPB;
  float4 stg[PER]; int dst[PER];
  #pragma unroll
  for (int q = 0; q < PER; ++q) {
    int e = tid + q * TPB;
    if (e < NV) {
      int r = e / (H / 4), c = (e % (H / 4)) * 4;
      float4 v = *(const float4*)(x + sel[r] * LD + c);
      float t = tv[r];
      stg[q] = make_float4(v.x * t, v.y * t, v.z * t, v.w * t);
      dst[q] = r * LD + c;
    }
  }
  __syncthreads();
  #pragma unroll
  for (int q = 0; q < PER; ++q) {
    int e = tid + q * TPB;
    if (e < NV) *(float4*)(x + dst[q]) = stg[q];
  }
  __syncthreads();
  SCHED_FENCE();
  if (DOFILT && tid < KK) {
    unsigned long long nm = 0ull;
    #pragma unroll 1
    for (int c = 0; c < KK; ++c)
      nm |= ((oldrow >> sel[c]) & 1ull) << c;
    sh.adjS[tid] = nm;
    sh.dinvS[tid] = rsqrtf(1.f + (float)__popcll(nm));
  }
  readout<KK>(x, LD, tid, rm, rs);
  __syncthreads();
  SCHED_FENCE();
}

__global__ __launch_bounds__(TPB, 5) void sagpool_fused(
    const int* __restrict__ aa, const float* __restrict__ pos,
    const float* __restrict__ cdr, const float* __restrict__ adjG,
    const float* __restrict__ emb,
    const float* __restrict__ W1, const float* __restrict__ b1,
    const float* __restrict__ p1wl, const float* __restrict__ p1bl, const float* __restrict__ p1wr,
    const float* __restrict__ W2, const float* __restrict__ b2,
    const float* __restrict__ p2wl, const float* __restrict__ p2bl, const float* __restrict__ p2wr,
    const float* __restrict__ W3, const float* __restrict__ b3,
    const float* __restrict__ p3wl, const float* __restrict__ p3bl, const float* __restrict__ p3wr,
    const float* __restrict__ mW1, const float* __restrict__ mb1,
    const float* __restrict__ mW2, const float* __restrict__ mb2,
    const float* __restrict__ mW3, const float* __restrict__ mb3,
    float* __restrict__ out)
{
  __shared__ Shm sh;
  const int b   = blockIdx.x;
  const int tid = threadIdx.x;

  float* dinv64 = sh.B2 + 2372;            // [2372..2436)
  float* tvP    = sh.B2 + 2308;            // [2308..2340)
  int*   selP   = (int*)(sh.B2 + 2340);    // [2340..2372)
  float* uu1 = sh.B;        float* sv1 = sh.B + 64;    // stage-1 (B dead)
  float* uu23 = sh.B2;      float* sv23 = sh.B2 + 64;  // stages 2/3 (dbuf dead)

  float rm = 0.f, rs = 0.f;   // readout accumulators (feature = tid, tid < 128)

  // adjacency [64][64] -> 64-bit row masks (B row pads) + fused degree/dinv
  {
    const float* rp = adjG + (size_t)b * (N0 * N0) + (tid >> 2) * N0 + (tid & 3) * 16;
    unsigned long long mpart = 0ull;
    #pragma unroll
    for (int q = 0; q < 16; q += 4) {
      float4 v = *(const float4*)(rp + q);
      unsigned int bits = (v.x != 0.f ? 1u : 0u) | (v.y != 0.f ? 2u : 0u)
                        | (v.z != 0.f ? 4u : 0u) | (v.w != 0.f ? 8u : 0u);
      mpart |= (unsigned long long)bits << q;
    }
    mpart <<= ((tid & 3) * 16);
    mpart |= __shfl_xor(mpart, 1, 64);
    mpart |= __shfl_xor(mpart, 2, 64);
    if ((tid & 3) == 0) {
      int r = tid >> 2;
      adjPad(sh.B, r) = mpart;
      dinv64[r] = rsqrtf(1.f + (float)__popcll(mpart));
    }
  }
  SCHED_FENCE();
  // build xin = [emb[aa] | pos | is_cdr3 | 0 0] -> B2 [64][36]
  #pragma unroll 1
  for (int e = tid; e < N0 * 36; e += TPB) {
    int j = e / 36, k = e - j * 36;
    int node = b * N0 + j;
    float v;
    if (k < 32)       v = emb[aa[node] * 32 + k];
    else if (k == 32) v = pos[node];
    else if (k == 33) v = cdr[node];
    else              v = 0.f;
    sh.B2[e] = v;
  }
  __syncthreads();
  SCHED_FENCE();

  // ---- stage 1: GCN(34->128) on 64 nodes, pool 64->32 (y1 never stored) ----
  agg_inplace<64, 3, 12, 36, true>(sh.B2, sh.B, dinv64, tid);  // xin -> z1 in place
  gemm_gw<64, 36, 34, 1>(sh.B2, 36, W1, b1, nullptr, 0, p1wl, p1wr,
                         uu1, sv1, nullptr, nullptr, tid);
  __syncthreads();
  SCHED_FENCE();
  score<64, true>(sh.B, uu1, sv1, p1bl[0], tid);
  __syncthreads();
  rank_topk<64, 32, 4>(sv1, tvP, selP, tid);
  __syncthreads();
  SCHED_FENCE();
  gemm_gw<32, 36, 34, 2>(sh.B2, 36, W1, b1, sh.B, LD, nullptr, nullptr,
                         nullptr, nullptr, tvP, selP, tid);    // x2 -> B rows 0..31
  __syncthreads();
  SCHED_FENCE();
  if (tid < 32) {   // adjPad rows still valid (cols 128+ untouched by x2)
    unsigned long long oldrow = adjPad(sh.B, selP[tid]);
    unsigned long long nm = 0ull;
    #pragma unroll 1
    for (int c = 0; c < 32; ++c)
      nm |= ((oldrow >> selP[c]) & 1ull) << c;
    sh.adjS[tid] = nm;
    sh.dinvS[tid] = rsqrtf(1.f + (float)__popcll(nm));
  }
  readout<32>(sh.B, LD, tid, rm, rs);
  __syncthreads();
  SCHED_FENCE();

  // ---- stage 2: GCN(128->128) on 32 nodes, pool 32->16 ----
  agg_inplace<32, 8, 16, LD, false>(sh.B, (float*)sh.adjS, sh.dinvS, tid);
  gemm128_lds<32>(sh.B, sh.B2, sh.B2 + 1024, W2, b2, tid);     // y2 in place
  __syncthreads();
  SCHED_FENCE();
  sag_pool_inplace<32, 16, 4, 8, true>(sh, sh.B, p2wl, p2bl, p2wr,
                                       uu23, sv23, tvP, selP, tid, rm, rs);

  // ---- stage 3: GCN(128->128) on 16 nodes, pool 16->8 ----
  agg_inplace<16, 16, 8, LD, false>(sh.B, (float*)sh.adjS, sh.dinvS, tid);
  gemm128_lds<16>(sh.B, sh.B2, sh.B2 + 1024, W3, b3, tid);     // y3 in place
  __syncthreads();
  SCHED_FENCE();
  sag_pool_inplace<16, 8, 8, 16, false>(sh, sh.B, p3wl, p3bl, p3wr,
                                        uu23, sv23, tvP, selP, tid, rm, rs);

  // ---- MLP head (B2[0..896) dead: rbuf[0..256) | h1[256..384) | h1p[384..640) | h2p[640..896)) ----
  if (tid < H) { sh.B2[tid] = rm; sh.B2[H + tid] = rs; }
  __syncthreads();
  SCHED_FENCE();
  { // h1 partials: 128 f x 2 k-halves
    int f = tid & (H - 1), p = tid >> 7;
    const int base = p * 128;
    float a = 0.f;
    #pragma unroll 4
    for (int k = 0; k < 128; ++k) a += sh.B2[base + k] * mW1[(base + k) * H + f];
    sh.B2[384 + p * H + f] = a;
  }
  __syncthreads();
  SCHED_FENCE();
  if (tid < H) {
    float a = mb1[tid] + sh.B2[384 + tid] + sh.B2[384 + H + tid];
    sh.B2[256 + tid] = fmaxf(a, 0.f);
  }
  __syncthreads();
  SCHED_FENCE();
  { // h2 partials: 64 o x 4 k-parts
    int o = tid & 63, p = tid >> 6;
    const int base = p * 32;
    float a = 0.f;
    #pragma unroll 4
    for (int k = 0; k < 32; ++k) a += sh.B2[256 + base + k] * mW2[(base + k) * 64 + o];
    sh.B2[640 + p * 64 + o] = a;
  }
  __syncthreads();
  SCHED_FENCE();
  if (tid < 64) {
    float a = sh.B2[640 + tid] + sh.B2[704 + tid] + sh.B2[768 + tid] + sh.B2[832 + tid];
    a = fmaxf(a + mb2[tid], 0.f);
    float v = a * mW3[tid];
    v = redsum<64>(v);
    if (tid == 0) out[b] = v + mb3[0];
  }
}

extern "C" void kernel_launch(void* const* d_in, const int* in_sizes, int n_in,
                              void* d_out, int out_size, void* d_ws, size_t ws_size,
                              hipStream_t stream) {
  (void)n_in; (void)d_ws; (void)ws_size; (void)out_size;
  const int*   aa   = (const int*)  d_in[0];
  const float* pos  = (const float*)d_in[1];
  const float* cdr  = (const float*)d_in[2];
  const float* adj  = (const float*)d_in[3];
  const float* emb  = (const float*)d_in[4];
  const float* W1   = (const float*)d_in[5];
  const float* b1   = (const float*)d_in[6];
  const float* p1wl = (const float*)d_in[7];
  const float* p1bl = (const float*)d_in[8];
  const float* p1wr = (const float*)d_in[9];
  const float* W2   = (const float*)d_in[10];
  const float* b2   = (const float*)d_in[11];
  const float* p2wl = (const float*)d_in[12];
  const float* p2bl = (const float*)d_in[13];
  const float* p2wr = (const float*)d_in[14];
  const float* W3   = (const float*)d_in[15];
  const float* b3   = (const float*)d_in[16];
  const float* p3wl = (const float*)d_in[17];
  const float* p3bl = (const float*)d_in[18];
  const float* p3wr = (const float*)d_in[19];
  const float* mW1  = (const float*)d_in[20];
  const float* mb1  = (const float*)d_in[21];
  const float* mW2  = (const float*)d_in[22];
  const float* mb2  = (const float*)d_in[23];
  const float* mW3  = (const float*)d_in[24];
  const float* mb3  = (const float*)d_in[25];
  float* out = (float*)d_out;

  const int B = in_sizes[0] / N0;  // 4096
  hipLaunchKernelGGL(sagpool_fused, dim3(B), dim3(TPB), 0, stream,
                     aa, pos, cdr, adj, emb,
                     W1, b1, p1wl, p1bl, p1wr,
                     W2, b2, p2wl, p2bl, p2wr,
                     W3, b3, p3wl, p3bl, p3wr,
                     mW1, mb1, mW2, mb2, mW3, mb3, out);
}

// Round 19
// 245.009 us; speedup vs baseline: 1.1288x; 1.0027x over previous
//
#include <hip/hip_runtime.h>
#include <math.h>

#define TPB 256
static constexpr int N0 = 64;   // nodes per graph
static constexpr int H  = 128;  // hidden
static constexpr int LD = 132;  // stride of the stage-2/3 buffer (bank-skew + 16B aligned)

#define SCHED_FENCE() __builtin_amdgcn_sched_barrier(0)

typedef const __attribute__((address_space(1))) unsigned int glb_u32;
typedef __attribute__((address_space(3))) unsigned int lds_u32;

// 26496 B -> 6 blocks/CU under the MEASURED 2048-B LDS granularity
// (26496 -> 26624; 26624*6 = 159744 <= 163840).  launch_bounds stays (.,5):
// R17 lesson — forcing 6 makes the allocator spill (40 VGPR + scratch).
// Lifetime aliasing (all verified):
//   adjM64          -> B row pads (cols 128..131; data never touches them)
//   dinv64          -> adjS region (adjS written only at stage-1 filter,
//                      after dinv64's last read in stage-1 agg)
//   tv1/sel1        -> adjS region too (dinv64 dead after agg; filter writes
//                      adjS after all tv/sel reads — single-wave lockstep)
//   uu/sv (stage 1) -> B[0..128)      (B dead until x2 recompute)
//   uu/sv (stage2/3)-> B2[0..128)     (W dbuf dead after its gemm)
//   tv/sel (st 2/3) -> B2[128..192)   (same dead dbuf region)
//   W dbuf (K=128)  -> B2[0..2048)    (z1 dead by then)
struct alignas(16) Shm {
  float B[32 * LD];             // 16896 B
  float B2[2304];               // 9216 B (xin/z1 [64][36] exactly; no pad: K=36)
  float dinvS[32];              // 128 B
  unsigned long long adjS[32];  // 256 B
};

__device__ __forceinline__ unsigned long long& adjPad(float* Bb, int i) {
  return *((unsigned long long*)(Bb + (i >> 1) * LD + 128) + (i & 1));
}

template<int W>
__device__ __forceinline__ float redsum(float v) {
  #pragma unroll
  for (int m = W >> 1; m; m >>= 1) v += __shfl_xor(v, m, 64);
  return v;
}
template<int W>
__device__ __forceinline__ int redsum_i(int v) {
  #pragma unroll
  for (int m = W >> 1; m; m >>= 1) v += __shfl_xor(v, m, 64);
  return v;
}

// In-place normalized aggregation: buf = D^-1/2 (A+I) D^-1/2 buf.
// PADJ: adjacency rows live in B row pads; else flat ull array.
template<int NN, int GROUPS, int CPT, int STRIDE, bool PADJ>
__device__ __forceinline__ void agg_inplace(float* buf, float* adjb,
    const float* dinv, int tid) {
  float acc[CPT];
  const int i = tid & (NN - 1);
  const int g = tid / NN;
  const bool act = (g < GROUPS);
  if (act) {
    unsigned long long m =
        (PADJ ? adjPad(adjb, i) : ((const unsigned long long*)adjb)[i]) | (1ull << i);
    #pragma unroll
    for (int c = 0; c < CPT; ++c) acc[c] = 0.f;
    const float* base = buf + g * CPT;
    #pragma unroll 1
    while (m) {
      int j = __builtin_ctzll(m); m &= m - 1;
      float a = dinv[j];
      const float* xp = base + j * STRIDE;
      #pragma unroll
      for (int c = 0; c < CPT; c += 4) {
        float4 xv = *(const float4*)(xp + c);
        acc[c]     += a * xv.x; acc[c + 1] += a * xv.y;
        acc[c + 2] += a * xv.z; acc[c + 3] += a * xv.w;
      }
    }
    float di = dinv[i];
    #pragma unroll
    for (int c = 0; c < CPT; ++c) acc[c] *= di;
  }
  __syncthreads();
  if (act) {
    float* op = buf + i * STRIDE + g * CPT;
    #pragma unroll
    for (int c = 0; c < CPT; c += 4)
      *(float4*)(op + c) = make_float4(acc[c], acc[c + 1], acc[c + 2], acc[c + 3]);
  }
  __syncthreads();
  SCHED_FENCE();
}

// Stage-1 GEMM (K=36), W streamed from global in float4 (4 cols/thread), depth-1.
// MODE 1: y in regs; u=y.wl, v=y.wr via redsum<32> -> uuP, svP.
// MODE 2: rows gathered via selP; out[r][fc..] = relu(acc+b) * tvP[r].
template<int R, int K, int KREAL, int MODE>
__device__ __forceinline__ void gemm_gw(const float* z, int zld,
    const float* __restrict__ Wg, const float* __restrict__ bg,
    float* out, int old_,
    const float* __restrict__ wl, const float* __restrict__ wr,
    float* uuP, float* svP, const float* tvP, const int* selP, int tid) {
  constexpr int NR = R / 8;
  constexpr int KC = 4;
  const int fc = (tid & 31) * 4;
  const int r0 = (tid >> 5) * NR;
  float4 acc[NR];
  int zoff[NR];
  #pragma unroll
  for (int r = 0; r < NR; ++r) {
    acc[r] = make_float4(0.f, 0.f, 0.f, 0.f);
    int row = (MODE == 2) ? selP[r0 + r] : (r0 + r);
    zoff[r] = row * zld;
  }
  float4 w[KC], nw[KC];
  #pragma unroll
  for (int k = 0; k < KC; ++k)
    w[k] = (k < KREAL) ? *(const float4*)(Wg + k * H + fc)
                       : make_float4(0.f, 0.f, 0.f, 0.f);
  #pragma unroll 1
  for (int kt = 0; kt < K; kt += KC) {
    if (kt + KC < K) {
      #pragma unroll
      for (int k = 0; k < KC; ++k) {
        int gr = kt + KC + k;
        nw[k] = (gr < KREAL) ? *(const float4*)(Wg + gr * H + fc)
                             : make_float4(0.f, 0.f, 0.f, 0.f);
      }
    }
    #pragma unroll
    for (int r = 0; r < NR; ++r) {
      float4 zv = *(const float4*)(z + zoff[r] + kt);
      acc[r].x += zv.x * w[0].x + zv.y * w[1].x + zv.z * w[2].x + zv.w * w[3].x;
      acc[r].y += zv.x * w[0].y + zv.y * w[1].y + zv.z * w[2].y + zv.w * w[3].y;
      acc[r].z += zv.x * w[0].z + zv.y * w[1].z + zv.z * w[2].z + zv.w * w[3].z;
      acc[r].w += zv.x * w[0].w + zv.y * w[1].w + zv.z * w[2].w + zv.w * w[3].w;
    }
    #pragma unroll
    for (int k = 0; k < KC; ++k) w[k] = nw[k];
  }
  const float4 b4 = *(const float4*)(bg + fc);
  if constexpr (MODE == 1) {
    const float4 wl4 = *(const float4*)(wl + fc);
    const float4 wr4 = *(const float4*)(wr + fc);
    #pragma unroll
    for (int r = 0; r < NR; ++r) {
      float y0 = fmaxf(acc[r].x + b4.x, 0.f);
      float y1 = fmaxf(acc[r].y + b4.y, 0.f);
      float y2 = fmaxf(acc[r].z + b4.z, 0.f);
      float y3 = fmaxf(acc[r].w + b4.w, 0.f);
      float up = y0 * wl4.x + y1 * wl4.y + y2 * wl4.z + y3 * wl4.w;
      float vp = y0 * wr4.x + y1 * wr4.y + y2 * wr4.z + y3 * wr4.w;
      up = redsum<32>(up);
      vp = redsum<32>(vp);
      if ((tid & 31) == 0) { uuP[r0 + r] = up; svP[r0 + r] = vp; }
    }
  } else {
    #pragma unroll
    for (int r = 0; r < NR; ++r) {
      float t = (MODE == 2) ? tvP[r0 + r] : 1.f;
      float4 o;
      o.x = fmaxf(acc[r].x + b4.x, 0.f) * t;
      o.y = fmaxf(acc[r].y + b4.y, 0.f) * t;
      o.z = fmaxf(acc[r].z + b4.z, 0.f) * t;
      o.w = fmaxf(acc[r].w + b4.w, 0.f) * t;
      *(float4*)(out + (r0 + r) * old_ + fc) = o;
    }
  }
}

// Async-DMA one 8-row W tile (8x128 floats = 4096 B, contiguous in global)
// into LDS: 4 waves x 1024 B each. LDS dest wave-uniform; global src per-lane.
__device__ __forceinline__ void stage_w8(const float* gsrc, float* ldst,
                                         int wv, int ln) {
  __builtin_amdgcn_global_load_lds(
      (glb_u32*)(gsrc + wv * 256 + ln * 4),
      (lds_u32*)(ldst + wv * 256),
      16, 0, 0);
}

// K=KREAL=128 GEMM, in-place (out aliases z), W tiles double-buffered in LDS
// (wt0/wt1, 1024 floats each) via async global_load_lds. Ascending-k order.
// R15 lesson: never register-double-buffer W (allocator spills to scratch).
template<int R>
__device__ __forceinline__ void gemm128_lds(float* zb,
    float* wt0, float* wt1,
    const float* __restrict__ Wg, const float* __restrict__ bg, int tid) {
  constexpr int NR = R / 8;
  const int fc = (tid & 31) * 4;
  const int r0 = (tid >> 5) * NR;
  const int wv = tid >> 6;
  const int ln = tid & 63;
  float4 acc[NR];
  int zoff[NR];
  #pragma unroll
  for (int r = 0; r < NR; ++r) {
    acc[r] = make_float4(0.f, 0.f, 0.f, 0.f);
    zoff[r] = (r0 + r) * LD;
  }
  stage_w8(Wg, wt0, wv, ln);
  asm volatile("s_waitcnt vmcnt(0)" ::: "memory");
  __syncthreads();
  #pragma unroll 1
  for (int kt = 0; kt < 128; kt += 8) {
    const int t = kt >> 3;
    const float* cur = (t & 1) ? wt1 : wt0;
    float* nxt = (t & 1) ? wt0 : wt1;
    if (kt + 8 < 128) stage_w8(Wg + (kt + 8) * H, nxt, wv, ln);
    #pragma unroll
    for (int kc = 0; kc < 8; kc += 4) {
      float4 w0 = *(const float4*)(cur + (kc + 0) * H + fc);
      float4 w1 = *(const float4*)(cur + (kc + 1) * H + fc);
      float4 w2 = *(const float4*)(cur + (kc + 2) * H + fc);
      float4 w3 = *(const float4*)(cur + (kc + 3) * H + fc);
      #pragma unroll
      for (int r = 0; r < NR; ++r) {
        float4 zv = *(const float4*)(zb + zoff[r] + kt + kc);
        acc[r].x += zv.x * w0.x + zv.y * w1.x + zv.z * w2.x + zv.w * w3.x;
        acc[r].y += zv.x * w0.y + zv.y * w1.y + zv.z * w2.y + zv.w * w3.y;
        acc[r].z += zv.x * w0.z + zv.y * w1.z + zv.z * w2.z + zv.w * w3.z;
        acc[r].w += zv.x * w0.w + zv.y * w1.w + zv.z * w2.w + zv.w * w3.w;
      }
    }
    asm volatile("s_waitcnt vmcnt(0)" ::: "memory");
    __syncthreads();   // next tile ready; final iter: all z reads complete
  }
  const float4 b4 = *(const float4*)(bg + fc);
  #pragma unroll
  for (int r = 0; r < NR; ++r) {
    float4 o;
    o.x = fmaxf(acc[r].x + b4.x, 0.f);
    o.y = fmaxf(acc[r].y + b4.y, 0.f);
    o.z = fmaxf(acc[r].z + b4.z, 0.f);
    o.w = fmaxf(acc[r].w + b4.w, 0.f);
    *(float4*)(zb + zoff[r] + fc) = o;
  }
}

// s[i] = sum_{j in nbr(i)} u[j] + bl + v[i]   (v already in sv[i])
template<int NN, bool PADJ>
__device__ __forceinline__ void score(float* adjb, const float* uu, float* sv,
                                      float bl, int tid) {
  if (tid < NN) {
    unsigned long long m =
        PADJ ? adjPad(adjb, tid) : ((const unsigned long long*)adjb)[tid];
    float a = bl + sv[tid];
    #pragma unroll 1
    while (m) { int j = __builtin_ctzll(m); m &= m - 1; a += uu[j]; }
    sv[tid] = a;
  }
}

// exact stable top-k via parallel rank counting (NN*RKP == TPB)
template<int NN, int KK, int RKP>
__device__ __forceinline__ void rank_topk(const float* sv, float* tv, int* sel,
                                          int tid) {
  int i = tid / RKP, p = tid % RKP;
  constexpr int CHr = NN / RKP;
  float si = sv[i];
  int cnt = 0;
  #pragma unroll
  for (int c = 0; c < CHr; ++c) {
    int j = p * CHr + c;
    float sj = sv[j];
    cnt += (sj > si || (sj == si && j < i)) ? 1 : 0;
  }
  cnt = redsum_i<RKP>(cnt);
  if (p == 0 && cnt < KK) { sel[cnt] = i; tv[cnt] = tanhf(si); }
}

// readout accumulate over KK rows of xn (stride ld)
template<int KK>
__device__ __forceinline__ void readout(const float* xn, int ld, int tid,
                                        float& rm, float& rs) {
  if (tid < H) {
    float m = -INFINITY, s = 0.f;
    #pragma unroll
    for (int r = 0; r < KK; ++r) {
      float v = xn[r * ld + tid];
      m = fmaxf(m, v); s += v;
    }
    rm += m;
    rs += s * (1.f / KK);
  }
}

// SAGPool for stages 2/3, fully IN PLACE on x (= y, stride LD).
template<int NN, int KK, int UVP, int RKP, bool DOFILT>
__device__ __forceinline__ void sag_pool_inplace(Shm& sh, float* x,
    const float* __restrict__ wl, const float* __restrict__ blp,
    const float* __restrict__ wr,
    float* uu, float* sv, float* tv, int* sel, int tid, float& rm, float& rs) {
  { // u[j]=y[j].wl -> uu, v[j]=y[j].wr -> sv  (2*NN*UVP == TPB)
    int dot = tid / UVP, p = tid % UVP;
    int j = dot >> 1;
    const float* wp = (dot & 1) ? wr : wl;
    constexpr int CH = H / UVP;
    const float* xr = x + j * LD + p * CH;
    const float* wq = wp + p * CH;
    float a = 0.f;
    #pragma unroll
    for (int k = 0; k < CH; k += 4) {
      float4 xv = *(const float4*)(xr + k);
      float4 wv = *(const float4*)(wq + k);
      a += xv.x * wv.x + xv.y * wv.y + xv.z * wv.z + xv.w * wv.w;
    }
    a = redsum<UVP>(a);
    if (p == 0) { if (dot & 1) sv[j] = a; else uu[j] = a; }
  }
  __syncthreads();
  SCHED_FENCE();
  score<NN, false>((float*)sh.adjS, uu, sv, blp[0], tid);
  __syncthreads();
  rank_topk<NN, KK, RKP>(sv, tv, sel, tid);
  __syncthreads();
  SCHED_FENCE();
  // snapshot old rows; reg-staged in-place gather x[r] = y[sel[r]] * tv[r]
  unsigned long long oldrow = 0ull;
  if (tid < KK) oldrow = sh.adjS[sel[tid]];
  constexpr int NV  = KK * (H / 4);
  constexpr int PER = (NV + TPB - 1) / TPB;
  float4 stg[PER]; int dst[PER];
  #pragma unroll
  for (int q = 0; q < PER; ++q) {
    int e = tid + q * TPB;
    if (e < NV) {
      int r = e / (H / 4), c = (e % (H / 4)) * 4;
      float4 v = *(const float4*)(x + sel[r] * LD + c);
      float t = tv[r];
      stg[q] = make_float4(v.x * t, v.y * t, v.z * t, v.w * t);
      dst[q] = r * LD + c;
    }
  }
  __syncthreads();
  #pragma unroll
  for (int q = 0; q < PER; ++q) {
    int e = tid + q * TPB;
    if (e < NV) *(float4*)(x + dst[q]) = stg[q];
  }
  __syncthreads();
  SCHED_FENCE();
  if (DOFILT && tid < KK) {
    unsigned long long nm = 0ull;
    #pragma unroll 1
    for (int c = 0; c < KK; ++c)
      nm |= ((oldrow >> sel[c]) & 1ull) << c;
    sh.adjS[tid] = nm;
    sh.dinvS[tid] = rsqrtf(1.f + (float)__popcll(nm));
  }
  readout<KK>(x, LD, tid, rm, rs);
  __syncthreads();
  SCHED_FENCE();
}

__global__ __launch_bounds__(TPB, 5) void sagpool_fused(
    const int* __restrict__ aa, const float* __restrict__ pos,
    const float* __restrict__ cdr, const float* __restrict__ adjG,
    const float* __restrict__ emb,
    const float* __restrict__ W1, const float* __restrict__ b1,
    const float* __restrict__ p1wl, const float* __restrict__ p1bl, const float* __restrict__ p1wr,
    const float* __restrict__ W2, const float* __restrict__ b2,
    const float* __restrict__ p2wl, const float* __restrict__ p2bl, const float* __restrict__ p2wr,
    const float* __restrict__ W3, const float* __restrict__ b3,
    const float* __restrict__ p3wl, const float* __restrict__ p3bl, const float* __restrict__ p3wr,
    const float* __restrict__ mW1, const float* __restrict__ mb1,
    const float* __restrict__ mW2, const float* __restrict__ mb2,
    const float* __restrict__ mW3, const float* __restrict__ mb3,
    float* __restrict__ out)
{
  __shared__ Shm sh;
  const int b   = blockIdx.x;
  const int tid = threadIdx.x;

  // stage-1 aliases into adjS/dinvS (both dead until the stage-1 filter):
  float* dinv64 = (float*)sh.adjS;            // 64 floats (dead after stage-1 agg)
  float* tv1    = (float*)sh.adjS;            // 32 floats (written at rank, after agg)
  int*   sel1   = (int*)sh.adjS + 32;         // 32 ints
  float* uu1 = sh.B;        float* sv1 = sh.B + 64;    // stage-1 (B dead)
  // stage-2/3 scratch in the dead W-dbuf region of B2:
  float* uu23 = sh.B2;      float* sv23 = sh.B2 + 64;
  float* tv23 = sh.B2 + 128; int* sel23 = (int*)(sh.B2 + 160);

  float rm = 0.f, rs = 0.f;   // readout accumulators (feature = tid, tid < 128)

  // adjacency [64][64] -> 64-bit row masks (B row pads) + fused degree/dinv
  {
    const float* rp = adjG + (size_t)b * (N0 * N0) + (tid >> 2) * N0 + (tid & 3) * 16;
    unsigned long long mpart = 0ull;
    #pragma unroll
    for (int q = 0; q < 16; q += 4) {
      float4 v = *(const float4*)(rp + q);
      unsigned int bits = (v.x != 0.f ? 1u : 0u) | (v.y != 0.f ? 2u : 0u)
                        | (v.z != 0.f ? 4u : 0u) | (v.w != 0.f ? 8u : 0u);
      mpart |= (unsigned long long)bits << q;
    }
    mpart <<= ((tid & 3) * 16);
    mpart |= __shfl_xor(mpart, 1, 64);
    mpart |= __shfl_xor(mpart, 2, 64);
    if ((tid & 3) == 0) {
      int r = tid >> 2;
      adjPad(sh.B, r) = mpart;
      dinv64[r] = rsqrtf(1.f + (float)__popcll(mpart));
    }
  }
  SCHED_FENCE();
  // build xin = [emb[aa] | pos | is_cdr3 | 0 0] -> B2 [64][36]
  #pragma unroll 1
  for (int e = tid; e < N0 * 36; e += TPB) {
    int j = e / 36, k = e - j * 36;
    int node = b * N0 + j;
    float v;
    if (k < 32)       v = emb[aa[node] * 32 + k];
    else if (k == 32) v = pos[node];
    else if (k == 33) v = cdr[node];
    else              v = 0.f;
    sh.B2[e] = v;
  }
  __syncthreads();
  SCHED_FENCE();

  // ---- stage 1: GCN(34->128) on 64 nodes, pool 64->32 (y1 never stored) ----
  agg_inplace<64, 3, 12, 36, true>(sh.B2, sh.B, dinv64, tid);  // xin -> z1 in place
  gemm_gw<64, 36, 34, 1>(sh.B2, 36, W1, b1, nullptr, 0, p1wl, p1wr,
                         uu1, sv1, nullptr, nullptr, tid);
  __syncthreads();
  SCHED_FENCE();
  score<64, true>(sh.B, uu1, sv1, p1bl[0], tid);
  __syncthreads();
  rank_topk<64, 32, 4>(sv1, tv1, sel1, tid);   // tv1/sel1 overwrite dead dinv64
  __syncthreads();
  SCHED_FENCE();
  gemm_gw<32, 36, 34, 2>(sh.B2, 36, W1, b1, sh.B, LD, nullptr, nullptr,
                         nullptr, nullptr, tv1, sel1, tid);    // x2 -> B rows 0..31
  __syncthreads();
  SCHED_FENCE();
  if (tid < 32) {   // adjPad rows still valid; single-wave: all sel1 reads
    unsigned long long oldrow = adjPad(sh.B, sel1[tid]);       // precede the adjS
    unsigned long long nm = 0ull;                              // writes (lockstep)
    #pragma unroll 1
    for (int c = 0; c < 32; ++c)
      nm |= ((oldrow >> sel1[c]) & 1ull) << c;
    sh.adjS[tid] = nm;
    sh.dinvS[tid] = rsqrtf(1.f + (float)__popcll(nm));
  }
  readout<32>(sh.B, LD, tid, rm, rs);
  __syncthreads();
  SCHED_FENCE();

  // ---- stage 2: GCN(128->128) on 32 nodes, pool 32->16 ----
  agg_inplace<32, 8, 16, LD, false>(sh.B, (float*)sh.adjS, sh.dinvS, tid);
  gemm128_lds<32>(sh.B, sh.B2, sh.B2 + 1024, W2, b2, tid);     // y2 in place
  __syncthreads();
  SCHED_FENCE();
  sag_pool_inplace<32, 16, 4, 8, true>(sh, sh.B, p2wl, p2bl, p2wr,
                                       uu23, sv23, tv23, sel23, tid, rm, rs);

  // ---- stage 3: GCN(128->128) on 16 nodes, pool 16->8 ----
  agg_inplace<16, 16, 8, LD, false>(sh.B, (float*)sh.adjS, sh.dinvS, tid);
  gemm128_lds<16>(sh.B, sh.B2, sh.B2 + 1024, W3, b3, tid);     // y3 in place
  __syncthreads();
  SCHED_FENCE();
  sag_pool_inplace<16, 8, 8, 16, false>(sh, sh.B, p3wl, p3bl, p3wr,
                                        uu23, sv23, tv23, sel23, tid, rm, rs);

  // ---- MLP head (B2[0..896) dead: rbuf[0..256) | h1[256..384) | h1p[384..640) | h2p[640..896)) ----
  if (tid < H) { sh.B2[tid] = rm; sh.B2[H + tid] = rs; }
  __syncthreads();
  SCHED_FENCE();
  { // h1 partials: 128 f x 2 k-halves
    int f = tid & (H - 1), p = tid >> 7;
    const int base = p * 128;
    float a = 0.f;
    #pragma unroll 4
    for (int k = 0; k < 128; ++k) a += sh.B2[base + k] * mW1[(base + k) * H + f];
    sh.B2[384 + p * H + f] = a;
  }
  __syncthreads();
  SCHED_FENCE();
  if (tid < H) {
    float a = mb1[tid] + sh.B2[384 + tid] + sh.B2[384 + H + tid];
    sh.B2[256 + tid] = fmaxf(a, 0.f);
  }
  __syncthreads();
  SCHED_FENCE();
  { // h2 partials: 64 o x 4 k-parts
    int o = tid & 63, p = tid >> 6;
    const int base = p * 32;
    float a = 0.f;
    #pragma unroll 4
    for (int k = 0; k < 32; ++k) a += sh.B2[256 + base + k] * mW2[(base + k) * 64 + o];
    sh.B2[640 + p * 64 + o] = a;
  }
  __syncthreads();
  SCHED_FENCE();
  if (tid < 64) {
    float a = sh.B2[640 + tid] + sh.B2[704 + tid] + sh.B2[768 + tid] + sh.B2[832 + tid];
    a = fmaxf(a + mb2[tid], 0.f);
    float v = a * mW3[tid];
    v = redsum<64>(v);
    if (tid == 0) out[b] = v + mb3[0];
  }
}

extern "C" void kernel_launch(void* const* d_in, const int* in_sizes, int n_in,
                              void* d_out, int out_size, void* d_ws, size_t ws_size,
                              hipStream_t stream) {
  (void)n_in; (void)d_ws; (void)ws_size; (void)out_size;
  const int*   aa   = (const int*)  d_in[0];
  const float* pos  = (const float*)d_in[1];
  const float* cdr  = (const float*)d_in[2];
  const float* adj  = (const float*)d_in[3];
  const float* emb  = (const float*)d_in[4];
  const float* W1   = (const float*)d_in[5];
  const float* b1   = (const float*)d_in[6];
  const float* p1wl = (const float*)d_in[7];
  const float* p1bl = (const float*)d_in[8];
  const float* p1wr = (const float*)d_in[9];
  const float* W2   = (const float*)d_in[10];
  const float* b2   = (const float*)d_in[11];
  const float* p2wl = (const float*)d_in[12];
  const float* p2bl = (const float*)d_in[13];
  const float* p2wr = (const float*)d_in[14];
  const float* W3   = (const float*)d_in[15];
  const float* b3   = (const float*)d_in[16];
  const float* p3wl = (const float*)d_in[17];
  const float* p3bl = (const float*)d_in[18];
  const float* p3wr = (const float*)d_in[19];
  const float* mW1  = (const float*)d_in[20];
  const float* mb1  = (const float*)d_in[21];
  const float* mW2  = (const float*)d_in[22];
  const float* mb2  = (const float*)d_in[23];
  const float* mW3  = (const float*)d_in[24];
  const float* mb3  = (const float*)d_in[25];
  float* out = (float*)d_out;

  const int B = in_sizes[0] / N0;  // 4096
  hipLaunchKernelGGL(sagpool_fused, dim3(B), dim3(TPB), 0, stream,
                     aa, pos, cdr, adj, emb,
                     W1, b1, p1wl, p1bl, p1wr,
                     W2, b2, p2wl, p2bl, p2wr,
                     W3, b3, p3wl, p3bl, p3wr,
                     mW1, mb1, mW2, mb2, mW3, mb3, out);
}

// Round 20
// 221.551 us; speedup vs baseline: 1.2484x; 1.1059x over previous
//
#include <hip/hip_runtime.h>
#include <math.h>

#define TPB 256
static constexpr int N0 = 64;   // nodes per graph
static constexpr int H  = 128;  // hidden
static constexpr int LD = 132;  // stride of the node-feature buffer (bank-skew + 16B aligned)

#define SCHED_FENCE() __builtin_amdgcn_sched_barrier(0)

typedef const __attribute__((address_space(1))) unsigned int glb_u32;
typedef __attribute__((address_space(3))) unsigned int lds_u32;

// 26496 B struct (5-6 blocks/CU). R20 structure: GCN outputs (y) live ONLY in
// registers; pooling writes selected rows straight from regs via rkOf[] inverse
// map. No MODE2 recompute, no y writeback, no LDS u/v pass, no gather.
// Lifetime aliasing:
//   adjM64            -> B row pads (cols 128..131)
//   dinv64, tv1, sel1 -> adjS region (dead until stage-1 filter; single-wave
//                        lockstep makes filter's read-then-write safe)
//   uu1/sv1           -> B[0..128)   (B dead until x2 cond-write)
//   rkOf1             -> B2[0..64)   (z1 dead after stage-1 gemm)
//   uu/sv/tv/sel/rkOf (stages 2/3) -> B2[0..256) (W dbuf dead after its gemm)
//   W dbuf (K=128 gemms) -> B2[0..2048)
struct alignas(16) Shm {
  float B[32 * LD];             // 16896 B
  float B2[2304];               // 9216 B (xin/z1 [64][36])
  float dinvS[32];              // 128 B
  unsigned long long adjS[32];  // 256 B
};

__device__ __forceinline__ unsigned long long& adjPad(float* Bb, int i) {
  return *((unsigned long long*)(Bb + (i >> 1) * LD + 128) + (i & 1));
}

template<int W>
__device__ __forceinline__ float redsum(float v) {
  #pragma unroll
  for (int m = W >> 1; m; m >>= 1) v += __shfl_xor(v, m, 64);
  return v;
}
template<int W>
__device__ __forceinline__ int redsum_i(int v) {
  #pragma unroll
  for (int m = W >> 1; m; m >>= 1) v += __shfl_xor(v, m, 64);
  return v;
}

// In-place normalized aggregation: buf = D^-1/2 (A+I) D^-1/2 buf.
template<int NN, int GROUPS, int CPT, int STRIDE, bool PADJ>
__device__ __forceinline__ void agg_inplace(float* buf, float* adjb,
    const float* dinv, int tid) {
  float acc[CPT];
  const int i = tid & (NN - 1);
  const int g = tid / NN;
  const bool act = (g < GROUPS);
  if (act) {
    unsigned long long m =
        (PADJ ? adjPad(adjb, i) : ((const unsigned long long*)adjb)[i]) | (1ull << i);
    #pragma unroll
    for (int c = 0; c < CPT; ++c) acc[c] = 0.f;
    const float* base = buf + g * CPT;
    #pragma unroll 1
    while (m) {
      int j = __builtin_ctzll(m); m &= m - 1;
      float a = dinv[j];
      const float* xp = base + j * STRIDE;
      #pragma unroll
      for (int c = 0; c < CPT; c += 4) {
        float4 xv = *(const float4*)(xp + c);
        acc[c]     += a * xv.x; acc[c + 1] += a * xv.y;
        acc[c + 2] += a * xv.z; acc[c + 3] += a * xv.w;
      }
    }
    float di = dinv[i];
    #pragma unroll
    for (int c = 0; c < CPT; ++c) acc[c] *= di;
  }
  __syncthreads();
  if (act) {
    float* op = buf + i * STRIDE + g * CPT;
    #pragma unroll
    for (int c = 0; c < CPT; c += 4)
      *(float4*)(op + c) = make_float4(acc[c], acc[c + 1], acc[c + 2], acc[c + 3]);
  }
  __syncthreads();
  SCHED_FENCE();
}

// Stage-1 GEMM (K=36, KREAL=34), W from global, depth-1 prefetch.
// On return: acc[r] = y = relu(zW+b) (caller keeps it live through rank);
// u=y.wl, v=y.wr reduced via redsum<32> into uuP/svP.
template<int R, int K, int KREAL>
__device__ __forceinline__ void gemm_s1_uv(const float* z, int zld,
    const float* __restrict__ Wg, const float* __restrict__ bg,
    const float* __restrict__ wl, const float* __restrict__ wr,
    float* uuP, float* svP, float4* acc, int tid) {
  constexpr int NR = R / 8;
  constexpr int KC = 4;
  const int fc = (tid & 31) * 4;
  const int r0 = (tid >> 5) * NR;
  #pragma unroll
  for (int r = 0; r < NR; ++r) acc[r] = make_float4(0.f, 0.f, 0.f, 0.f);
  float4 w[KC], nw[KC];
  #pragma unroll
  for (int k = 0; k < KC; ++k)
    w[k] = (k < KREAL) ? *(const float4*)(Wg + k * H + fc)
                       : make_float4(0.f, 0.f, 0.f, 0.f);
  #pragma unroll 1
  for (int kt = 0; kt < K; kt += KC) {
    if (kt + KC < K) {
      #pragma unroll
      for (int k = 0; k < KC; ++k) {
        int gr = kt + KC + k;
        nw[k] = (gr < KREAL) ? *(const float4*)(Wg + gr * H + fc)
                             : make_float4(0.f, 0.f, 0.f, 0.f);
      }
    }
    #pragma unroll
    for (int r = 0; r < NR; ++r) {
      float4 zv = *(const float4*)(z + (r0 + r) * zld + kt);
      acc[r].x += zv.x * w[0].x + zv.y * w[1].x + zv.z * w[2].x + zv.w * w[3].x;
      acc[r].y += zv.x * w[0].y + zv.y * w[1].y + zv.z * w[2].y + zv.w * w[3].y;
      acc[r].z += zv.x * w[0].z + zv.y * w[1].z + zv.z * w[2].z + zv.w * w[3].z;
      acc[r].w += zv.x * w[0].w + zv.y * w[1].w + zv.z * w[2].w + zv.w * w[3].w;
    }
    #pragma unroll
    for (int k = 0; k < KC; ++k) w[k] = nw[k];
  }
  const float4 b4  = *(const float4*)(bg + fc);
  const float4 wl4 = *(const float4*)(wl + fc);
  const float4 wr4 = *(const float4*)(wr + fc);
  #pragma unroll
  for (int r = 0; r < NR; ++r) {
    float4 y;
    y.x = fmaxf(acc[r].x + b4.x, 0.f);
    y.y = fmaxf(acc[r].y + b4.y, 0.f);
    y.z = fmaxf(acc[r].z + b4.z, 0.f);
    y.w = fmaxf(acc[r].w + b4.w, 0.f);
    acc[r] = y;
    float up = y.x * wl4.x + y.y * wl4.y + y.z * wl4.z + y.w * wl4.w;
    float vp = y.x * wr4.x + y.y * wr4.y + y.z * wr4.z + y.w * wr4.w;
    up = redsum<32>(up);
    vp = redsum<32>(vp);
    if ((tid & 31) == 0) { uuP[r0 + r] = up; svP[r0 + r] = vp; }
  }
}

// Async-DMA one 8-row W tile (4096 B contiguous) into LDS (4 waves x 1024 B).
__device__ __forceinline__ void stage_w8(const float* gsrc, float* ldst,
                                         int wv, int ln) {
  __builtin_amdgcn_global_load_lds(
      (glb_u32*)(gsrc + wv * 256 + ln * 4),
      (lds_u32*)(ldst + wv * 256),
      16, 0, 0);
}

// K=128 GEMM reading z from LDS, W LDS-double-buffered (R15 lesson: never
// register-dbuf W). NO y writeback: acc[r] = y stays in regs; u/v reduced
// into uuP/svP. Ascending-k order (matches prior rounds).
template<int R>
__device__ __forceinline__ void gemm128_uv(const float* zb,
    float* wt0, float* wt1,
    const float* __restrict__ Wg, const float* __restrict__ bg,
    const float* __restrict__ wl, const float* __restrict__ wr,
    float* uuP, float* svP, float4* acc, int tid) {
  constexpr int NR = R / 8;
  const int fc = (tid & 31) * 4;
  const int r0 = (tid >> 5) * NR;
  const int wv = tid >> 6;
  const int ln = tid & 63;
  #pragma unroll
  for (int r = 0; r < NR; ++r) acc[r] = make_float4(0.f, 0.f, 0.f, 0.f);
  stage_w8(Wg, wt0, wv, ln);
  asm volatile("s_waitcnt vmcnt(0)" ::: "memory");
  __syncthreads();
  #pragma unroll 1
  for (int kt = 0; kt < 128; kt += 8) {
    const int t = kt >> 3;
    const float* cur = (t & 1) ? wt1 : wt0;
    float* nxt = (t & 1) ? wt0 : wt1;
    if (kt + 8 < 128) stage_w8(Wg + (kt + 8) * H, nxt, wv, ln);
    #pragma unroll
    for (int kc = 0; kc < 8; kc += 4) {
      float4 w0 = *(const float4*)(cur + (kc + 0) * H + fc);
      float4 w1 = *(const float4*)(cur + (kc + 1) * H + fc);
      float4 w2 = *(const float4*)(cur + (kc + 2) * H + fc);
      float4 w3 = *(const float4*)(cur + (kc + 3) * H + fc);
      #pragma unroll
      for (int r = 0; r < NR; ++r) {
        float4 zv = *(const float4*)(zb + (r0 + r) * LD + kt + kc);
        acc[r].x += zv.x * w0.x + zv.y * w1.x + zv.z * w2.x + zv.w * w3.x;
        acc[r].y += zv.x * w0.y + zv.y * w1.y + zv.z * w2.y + zv.w * w3.y;
        acc[r].z += zv.x * w0.z + zv.y * w1.z + zv.z * w2.z + zv.w * w3.z;
        acc[r].w += zv.x * w0.w + zv.y * w1.w + zv.z * w2.w + zv.w * w3.w;
      }
    }
    asm volatile("s_waitcnt vmcnt(0)" ::: "memory");
    __syncthreads();
  }
  const float4 b4  = *(const float4*)(bg + fc);
  const float4 wl4 = *(const float4*)(wl + fc);
  const float4 wr4 = *(const float4*)(wr + fc);
  #pragma unroll
  for (int r = 0; r < NR; ++r) {
    float4 y;
    y.x = fmaxf(acc[r].x + b4.x, 0.f);
    y.y = fmaxf(acc[r].y + b4.y, 0.f);
    y.z = fmaxf(acc[r].z + b4.z, 0.f);
    y.w = fmaxf(acc[r].w + b4.w, 0.f);
    acc[r] = y;
    float up = y.x * wl4.x + y.y * wl4.y + y.z * wl4.z + y.w * wl4.w;
    float vp = y.x * wr4.x + y.y * wr4.y + y.z * wr4.z + y.w * wr4.w;
    up = redsum<32>(up);
    vp = redsum<32>(vp);
    if ((tid & 31) == 0) { uuP[r0 + r] = up; svP[r0 + r] = vp; }
  }
}

// s[i] = sum_{j in nbr(i)} u[j] + bl + v[i]   (v already in sv[i])
template<int NN, bool PADJ>
__device__ __forceinline__ void score(float* adjb, const float* uu, float* sv,
                                      float bl, int tid) {
  if (tid < NN) {
    unsigned long long m =
        PADJ ? adjPad(adjb, tid) : ((const unsigned long long*)adjb)[tid];
    float a = bl + sv[tid];
    #pragma unroll 1
    while (m) { int j = __builtin_ctzll(m); m &= m - 1; a += uu[j]; }
    sv[tid] = a;
  }
}

// exact stable top-k via parallel rank counting (NN*RKP == TPB).
// Also writes the inverse map rkOf[node] = rank (or -1).
template<int NN, int KK, int RKP>
__device__ __forceinline__ void rank_topk_rk(const float* sv, float* tv,
    int* sel, int* rkOf, int tid) {
  int i = tid / RKP, p = tid % RKP;
  constexpr int CHr = NN / RKP;
  float si = sv[i];
  int cnt = 0;
  #pragma unroll
  for (int c = 0; c < CHr; ++c) {
    int j = p * CHr + c;
    float sj = sv[j];
    cnt += (sj > si || (sj == si && j < i)) ? 1 : 0;
  }
  cnt = redsum_i<RKP>(cnt);
  if (p == 0) {
    if (cnt < KK) { sel[cnt] = i; tv[cnt] = tanhf(si); }
    rkOf[i] = (cnt < KK) ? cnt : -1;
  }
}

// write selected rows from in-register y: out[rk][fc..] = y * tv[rk]
template<int NR>
__device__ __forceinline__ void cond_write(const float4* acc, const float* tv,
    const int* rkOf, float* out, int tid) {
  const int fc = (tid & 31) * 4;
  const int r0 = (tid >> 5) * NR;
  #pragma unroll
  for (int r = 0; r < NR; ++r) {
    int rk = rkOf[r0 + r];
    if (rk >= 0) {
      float t = tv[rk];
      *(float4*)(out + rk * LD + fc) =
          make_float4(acc[r].x * t, acc[r].y * t, acc[r].z * t, acc[r].w * t);
    }
  }
}

// readout accumulate over KK rows of xn (stride ld)
template<int KK>
__device__ __forceinline__ void readout(const float* xn, int ld, int tid,
                                        float& rm, float& rs) {
  if (tid < H) {
    float m = -INFINITY, s = 0.f;
    #pragma unroll
    for (int r = 0; r < KK; ++r) {
      float v = xn[r * ld + tid];
      m = fmaxf(m, v); s += v;
    }
    rm += m;
    rs += s * (1.f / KK);
  }
}

__global__ __launch_bounds__(TPB, 5) void sagpool_fused(
    const int* __restrict__ aa, const float* __restrict__ pos,
    const float* __restrict__ cdr, const float* __restrict__ adjG,
    const float* __restrict__ emb,
    const float* __restrict__ W1, const float* __restrict__ b1,
    const float* __restrict__ p1wl, const float* __restrict__ p1bl, const float* __restrict__ p1wr,
    const float* __restrict__ W2, const float* __restrict__ b2,
    const float* __restrict__ p2wl, const float* __restrict__ p2bl, const float* __restrict__ p2wr,
    const float* __restrict__ W3, const float* __restrict__ b3,
    const float* __restrict__ p3wl, const float* __restrict__ p3bl, const float* __restrict__ p3wr,
    const float* __restrict__ mW1, const float* __restrict__ mb1,
    const float* __restrict__ mW2, const float* __restrict__ mb2,
    const float* __restrict__ mW3, const float* __restrict__ mb3,
    float* __restrict__ out)
{
  __shared__ Shm sh;
  const int b   = blockIdx.x;
  const int tid = threadIdx.x;

  // stage-1 aliases (adjS region dead until stage-1 filter):
  float* dinv64 = (float*)sh.adjS;
  float* tv1    = (float*)sh.adjS;
  int*   sel1   = (int*)sh.adjS + 32;
  float* uu1 = sh.B;       float* sv1 = sh.B + 64;
  int*   rkOf1 = (int*)sh.B2;                        // z1 dead after stage-1 gemm
  // stage-2/3 scratch in dead W-dbuf region of B2:
  float* uu23 = sh.B2;      float* sv23 = sh.B2 + 64;
  float* tv23 = sh.B2 + 128; int* sel23 = (int*)(sh.B2 + 160);
  int*   rkOf23 = (int*)(sh.B2 + 192);

  float rm = 0.f, rs = 0.f;

  // adjacency [64][64] -> 64-bit row masks (B row pads) + fused degree/dinv
  {
    const float* rp = adjG + (size_t)b * (N0 * N0) + (tid >> 2) * N0 + (tid & 3) * 16;
    unsigned long long mpart = 0ull;
    #pragma unroll
    for (int q = 0; q < 16; q += 4) {
      float4 v = *(const float4*)(rp + q);
      unsigned int bits = (v.x != 0.f ? 1u : 0u) | (v.y != 0.f ? 2u : 0u)
                        | (v.z != 0.f ? 4u : 0u) | (v.w != 0.f ? 8u : 0u);
      mpart |= (unsigned long long)bits << q;
    }
    mpart <<= ((tid & 3) * 16);
    mpart |= __shfl_xor(mpart, 1, 64);
    mpart |= __shfl_xor(mpart, 2, 64);
    if ((tid & 3) == 0) {
      int r = tid >> 2;
      adjPad(sh.B, r) = mpart;
      dinv64[r] = rsqrtf(1.f + (float)__popcll(mpart));
    }
  }
  SCHED_FENCE();
  // build xin = [emb[aa] | pos | is_cdr3 | 0 0] -> B2 [64][36]
  #pragma unroll 1
  for (int e = tid; e < N0 * 36; e += TPB) {
    int j = e / 36, k = e - j * 36;
    int node = b * N0 + j;
    float v;
    if (k < 32)       v = emb[aa[node] * 32 + k];
    else if (k == 32) v = pos[node];
    else if (k == 33) v = cdr[node];
    else              v = 0.f;
    sh.B2[e] = v;
  }
  __syncthreads();
  SCHED_FENCE();

  // ---- stage 1: GCN(34->128) on 64 nodes, pool 64->32 ----
  agg_inplace<64, 3, 12, 36, true>(sh.B2, sh.B, dinv64, tid);
  float4 y1[8];
  gemm_s1_uv<64, 36, 34>(sh.B2, 36, W1, b1, p1wl, p1wr, uu1, sv1, y1, tid);
  __syncthreads();
  SCHED_FENCE();
  score<64, true>(sh.B, uu1, sv1, p1bl[0], tid);
  __syncthreads();
  rank_topk_rk<64, 32, 4>(sv1, tv1, sel1, rkOf1, tid);
  __syncthreads();
  SCHED_FENCE();
  cond_write<8>(y1, tv1, rkOf1, sh.B, tid);          // x2 -> B rows 0..31
  __syncthreads();
  SCHED_FENCE();
  if (tid < 32) {   // filter (adjPad intact; single-wave lockstep read->write)
    unsigned long long oldrow = adjPad(sh.B, sel1[tid]);
    unsigned long long nm = 0ull;
    #pragma unroll 1
    for (int c = 0; c < 32; ++c)
      nm |= ((oldrow >> sel1[c]) & 1ull) << c;
    sh.adjS[tid] = nm;
    sh.dinvS[tid] = rsqrtf(1.f + (float)__popcll(nm));
  }
  readout<32>(sh.B, LD, tid, rm, rs);
  __syncthreads();
  SCHED_FENCE();

  // ---- stage 2: GCN(128->128) on 32 nodes, pool 32->16 ----
  agg_inplace<32, 8, 16, LD, false>(sh.B, (float*)sh.adjS, sh.dinvS, tid);
  float4 y2[4];
  gemm128_uv<32>(sh.B, sh.B2, sh.B2 + 1024, W2, b2, p2wl, p2wr,
                 uu23, sv23, y2, tid);
  __syncthreads();
  SCHED_FENCE();
  score<32, false>((float*)sh.adjS, uu23, sv23, p2bl[0], tid);
  __syncthreads();
  rank_topk_rk<32, 16, 8>(sv23, tv23, sel23, rkOf23, tid);
  __syncthreads();
  SCHED_FENCE();
  cond_write<4>(y2, tv23, rkOf23, sh.B, tid);        // x3 -> B rows 0..15
  if (tid < 16) {   // filter (single-wave lockstep)
    unsigned long long oldrow = sh.adjS[sel23[tid]];
    unsigned long long nm = 0ull;
    #pragma unroll 1
    for (int c = 0; c < 16; ++c)
      nm |= ((oldrow >> sel23[c]) & 1ull) << c;
    sh.adjS[tid] = nm;
    sh.dinvS[tid] = rsqrtf(1.f + (float)__popcll(nm));
  }
  __syncthreads();
  SCHED_FENCE();
  readout<16>(sh.B, LD, tid, rm, rs);
  __syncthreads();
  SCHED_FENCE();

  // ---- stage 3: GCN(128->128) on 16 nodes, pool 16->8 ----
  agg_inplace<16, 16, 8, LD, false>(sh.B, (float*)sh.adjS, sh.dinvS, tid);
  float4 y3[2];
  gemm128_uv<16>(sh.B, sh.B2, sh.B2 + 1024, W3, b3, p3wl, p3wr,
                 uu23, sv23, y3, tid);
  __syncthreads();
  SCHED_FENCE();
  score<16, false>((float*)sh.adjS, uu23, sv23, p3bl[0], tid);
  __syncthreads();
  rank_topk_rk<16, 8, 16>(sv23, tv23, sel23, rkOf23, tid);
  __syncthreads();
  SCHED_FENCE();
  cond_write<2>(y3, tv23, rkOf23, sh.B, tid);        // x4 -> B rows 0..7
  __syncthreads();
  SCHED_FENCE();
  readout<8>(sh.B, LD, tid, rm, rs);
  __syncthreads();
  SCHED_FENCE();

  // ---- MLP head (B2[0..896) dead) ----
  if (tid < H) { sh.B2[tid] = rm; sh.B2[H + tid] = rs; }
  __syncthreads();
  SCHED_FENCE();
  { // h1 partials: 128 f x 2 k-halves
    int f = tid & (H - 1), p = tid >> 7;
    const int base = p * 128;
    float a = 0.f;
    #pragma unroll 4
    for (int k = 0; k < 128; ++k) a += sh.B2[base + k] * mW1[(base + k) * H + f];
    sh.B2[384 + p * H + f] = a;
  }
  __syncthreads();
  SCHED_FENCE();
  if (tid < H) {
    float a = mb1[tid] + sh.B2[384 + tid] + sh.B2[384 + H + tid];
    sh.B2[256 + tid] = fmaxf(a, 0.f);
  }
  __syncthreads();
  SCHED_FENCE();
  { // h2 partials: 64 o x 4 k-parts
    int o = tid & 63, p = tid >> 6;
    const int base = p * 32;
    float a = 0.f;
    #pragma unroll 4
    for (int k = 0; k < 32; ++k) a += sh.B2[256 + base + k] * mW2[(base + k) * 64 + o];
    sh.B2[640 + p * 64 + o] = a;
  }
  __syncthreads();
  SCHED_FENCE();
  if (tid < 64) {
    float a = sh.B2[640 + tid] + sh.B2[704 + tid] + sh.B2[768 + tid] + sh.B2[832 + tid];
    a = fmaxf(a + mb2[tid], 0.f);
    float v = a * mW3[tid];
    v = redsum<64>(v);
    if (tid == 0) out[b] = v + mb3[0];
  }
}

extern "C" void kernel_launch(void* const* d_in, const int* in_sizes, int n_in,
                              void* d_out, int out_size, void* d_ws, size_t ws_size,
                              hipStream_t stream) {
  (void)n_in; (void)d_ws; (void)ws_size; (void)out_size;
  const int*   aa   = (const int*)  d_in[0];
  const float* pos  = (const float*)d_in[1];
  const float* cdr  = (const float*)d_in[2];
  const float* adj  = (const float*)d_in[3];
  const float* emb  = (const float*)d_in[4];
  const float* W1   = (const float*)d_in[5];
  const float* b1   = (const float*)d_in[6];
  const float* p1wl = (const float*)d_in[7];
  const float* p1bl = (const float*)d_in[8];
  const float* p1wr = (const float*)d_in[9];
  const float* W2   = (const float*)d_in[10];
  const float* b2   = (const float*)d_in[11];
  const float* p2wl = (const float*)d_in[12];
  const float* p2bl = (const float*)d_in[13];
  const float* p2wr = (const float*)d_in[14];
  const float* W3   = (const float*)d_in[15];
  const float* b3   = (const float*)d_in[16];
  const float* p3wl = (const float*)d_in[17];
  const float* p3bl = (const float*)d_in[18];
  const float* p3wr = (const float*)d_in[19];
  const float* mW1  = (const float*)d_in[20];
  const float* mb1  = (const float*)d_in[21];
  const float* mW2  = (const float*)d_in[22];
  const float* mb2  = (const float*)d_in[23];
  const float* mW3  = (const float*)d_in[24];
  const float* mb3  = (const float*)d_in[25];
  float* out = (float*)d_out;

  const int B = in_sizes[0] / N0;  // 4096
  hipLaunchKernelGGL(sagpool_fused, dim3(B), dim3(TPB), 0, stream,
                     aa, pos, cdr, adj, emb,
                     W1, b1, p1wl, p1bl, p1wr,
                     W2, b2, p2wl, p2bl, p2wr,
                     W3, b3, p3wl, p3bl, p3wr,
                     mW1, mb1, mW2, mb2, mW3, mb3, out);
}